// Round 11
// baseline (222.126 us; speedup 1.0000x reference)
//
#include <hip/hip_runtime.h>

#define LEAK 0.01f
#define BS 128           // nodes per bucket (dl fits in 7 bits)
#define PCHUNK 4096      // edges per partition chunk (contiguous 32KB pair window)
#define PT 512           // threads for part (8 waves x 628 blocks -> ~19.6 waves/CU)
#define CT 512           // threads for conv kernels
#define MAXNB 256        // max buckets per graph (scan: 1 bin/thread; LDS arrays)
#define CPGMAX 256       // max chunks per graph (conv LDS run arrays)

__device__ __forceinline__ float lrelu(float v) {
    return v >= 0.f ? v : LEAK * v;
}

// ---- float <-> orderable-uint encoding for min (inf -> 0xFFFFFFFF) ----
__device__ __forceinline__ unsigned int fmin_encode(float x) {
    unsigned int u = __float_as_uint(x);
    return (u & 0x80000000u) ? ~u : (u | 0x80000000u);
}
__device__ __forceinline__ float fmin_decode(unsigned int k) {
    unsigned int u = (k & 0x80000000u) ? (k ^ 0x80000000u) : ~k;
    return __uint_as_float(u);
}

// block-reduce (any multiple-of-64 block) + one atomicAdd
__device__ __forceinline__ void block_add(float c, float* dst) {
    __shared__ float wsum[8];
#pragma unroll
    for (int off = 32; off > 0; off >>= 1) c += __shfl_down(c, off, 64);
    int lane = threadIdx.x & 63;
    int wave = threadIdx.x >> 6;
    if (lane == 0) wsum[wave] = c;
    __syncthreads();
    if (threadIdx.x == 0) {
        float s = 0.f;
        int nw = blockDim.x >> 6;
        for (int w = 0; w < nw; ++w) s += wsum[w];
        atomicAdd(dst, s);
    }
}

// ---------------------------------------------------------------------------
// init + layer-1 precompute + x0 pool contribution (x0 never materialized)
// ---------------------------------------------------------------------------
__global__ __launch_bounds__(256) void init_pre1_kernel(
    const int* __restrict__ nf, const float* __restrict__ act,
    const float* __restrict__ W1, const float* __restrict__ b1,
    const float* __restrict__ lw, const float* __restrict__ lb,
    float* __restrict__ a1, float* __restrict__ a2,
    float* __restrict__ out, int N) {
    int b = blockIdx.y;
    int n = blockIdx.x * 256 + threadIdx.x;
    float c = 0.f;
    if (n < N) {
        size_t i = (size_t)b * N + n;
        float x0 = (float)nf[i * 2 + 0];
        float x1 = (float)nf[i * 2 + 1];
        float x2 = act[i];
        float v1[8], v2[8];
#pragma unroll
        for (int j = 0; j < 8; ++j) {
            v1[j] = b1[j] + x0 * W1[0 * 8 + j] + x1 * W1[1 * 8 + j] + x2 * W1[2 * 8 + j];
            v2[j] =         x0 * W1[3 * 8 + j] + x1 * W1[4 * 8 + j] + x2 * W1[5 * 8 + j];
        }
        float4* o1 = (float4*)(a1 + i * 8);
        float4* o2 = (float4*)(a2 + i * 8);
        o1[0] = make_float4(v1[0], v1[1], v1[2], v1[3]);
        o1[1] = make_float4(v1[4], v1[5], v1[6], v1[7]);
        o2[0] = make_float4(v2[0], v2[1], v2[2], v2[3]);
        o2[1] = make_float4(v2[4], v2[5], v2[6], v2[7]);
        c = x0 * lw[0] + x1 * lw[1] + x2 * lw[2];
        if (n == 0) c += lb[0];
    }
    block_add(c, &out[b]);
}

// ---------------------------------------------------------------------------
// one-pass chunk-local partition: LDS hist (rank per edge) -> LDS scan ->
// chunk-major coalesced pair write + bin-major ofs export.
// ofs[b][bin][chunk] = run start of (bin, chunk); run end = ofs[b][bin+1][chunk]
// pair = { src | dl<<16 , ea_bits }
// ---------------------------------------------------------------------------
__global__ __launch_bounds__(PT) void part_kernel(
    const int* __restrict__ ei, const float* __restrict__ ea,
    int2* __restrict__ pairs, int* __restrict__ ofs,
    int E, int NB, int CPG) {
    __shared__ int lc[MAXNB];        // hist counts, then run starts
    __shared__ int lofs[MAXNB + 1];  // exclusive starts
    __shared__ int ts[PT];           // scan temp
    int b = blockIdx.y;
    int c = blockIdx.x;
    int t = threadIdx.x;
    for (int i = t; i < NB; i += PT) lc[i] = 0;
    __syncthreads();

    int e0 = c * PCHUNK;
    int end = min(e0 + PCHUNK, E);
    const int* srow = ei + (size_t)b * 2 * E;
    const int* drow = srow + E;

    // phase 1: hist with per-edge rank capture
    int pk[PCHUNK / PT];  // bin | dl<<10 | rank<<17
#pragma unroll
    for (int j = 0; j < PCHUNK / PT; ++j) {
        int e = e0 + j * PT + t;
        int p = -1;
        if (e < end) {
            int d = drow[e];
            int bin = d >> 7;
            int r = atomicAdd(&lc[bin], 1);
            p = bin | ((d & 127) << 10) | (r << 17);
        }
        pk[j] = p;
    }
    __syncthreads();

    // phase 2: exclusive scan over NB bins (thread t owns bin t; NB <= PT)
    int v = (t < NB) ? lc[t] : 0;
    ts[t] = v;
    __syncthreads();
    int incl = v;
    for (int off = 1; off < PT; off <<= 1) {
        int add = (t >= off) ? ts[t - off] : 0;
        __syncthreads();
        incl += add;
        ts[t] = incl;
        __syncthreads();
    }
    if (t < NB) lofs[t] = incl - v;
    if (t == PT - 1) lofs[NB] = incl;  // = end - e0
    __syncthreads();

    // export ofs (bin-major: [b][i][c]) + set run starts
    for (int i = t; i <= NB; i += PT) {
        int w = lofs[i];
        ofs[((size_t)b * (NB + 1) + i) * CPG + c] = w;
        if (i < NB) lc[i] = w;
    }
    __syncthreads();

    // phase 3: coalesced-window pair write (pos = start + rank, no atomics)
    size_t pbase = (size_t)b * E + e0;
#pragma unroll
    for (int j = 0; j < PCHUNK / PT; ++j) {
        int e = e0 + j * PT + t;
        if (e < end) {
            int p = pk[j];
            int bin = p & 1023;
            int dl = (p >> 10) & 127;
            int r = p >> 17;
            int pos = lc[bin] + r;
            pairs[pbase + pos] =
                make_int2(srow[e] | (dl << 16), __float_as_int(ea[(size_t)b * E + e]));
        }
    }
}

// ---------------------------------------------------------------------------
// bucket conv: one block per 128-node bucket; 32-lane sub-wave per run with
// software-pipelined next-chunk pair prefetch; LDS encoded-uint min acc
// ---------------------------------------------------------------------------

__device__ __forceinline__ void conv_edge_body(
    const float* __restrict__ a2g, const float* we, const float* bb,
    const float* __restrict__ W2, int2 p,
    const float* __restrict__ a1s, unsigned int* __restrict__ acc) {
    int srcn = p.x & 0xFFFF;
    int dl = (p.x >> 16) & 127;
    float eav = __int_as_float(p.y);
    const float4* q = (const float4*)(a2g + (size_t)srcn * 8);
    float4 lo = q[0], hi = q[1];
    float h1[8];
    h1[0] = a1s[dl * 9 + 0] + lo.x; h1[1] = a1s[dl * 9 + 1] + lo.y;
    h1[2] = a1s[dl * 9 + 2] + lo.z; h1[3] = a1s[dl * 9 + 3] + lo.w;
    h1[4] = a1s[dl * 9 + 4] + hi.x; h1[5] = a1s[dl * 9 + 5] + hi.y;
    h1[6] = a1s[dl * 9 + 6] + hi.z; h1[7] = a1s[dl * 9 + 7] + hi.w;
#pragma unroll
    for (int j = 0; j < 8; ++j) {
        h1[j] = fmaf(eav, we[j], h1[j]);
        h1[j] = lrelu(h1[j]);
    }
    float h2[8];
#pragma unroll
    for (int j = 0; j < 8; ++j) h2[j] = bb[j];
#pragma unroll
    for (int kk = 0; kk < 8; ++kk) {
        float hk = h1[kk];
#pragma unroll
        for (int j = 0; j < 8; ++j) h2[j] = fmaf(hk, W2[kk * 8 + j], h2[j]);
    }
#pragma unroll
    for (int j = 0; j < 8; ++j)
        atomicMin(&acc[dl * 9 + j], fmin_encode(h2[j]));
}

// iterate this bucket's run in every chunk; prefetch next chunk's pair while
// computing the current one (hides one L2 round-trip per chunk-chain)
__device__ __forceinline__ void conv_edges_runs(
    const float* __restrict__ a2g, const float* we, const float* bb,
    const float* __restrict__ W2, const int2* __restrict__ pairsg,
    const int* __restrict__ ofb, int CPG,
    const float* __restrict__ a1s, unsigned int* __restrict__ acc,
    int* __restrict__ rs, int* __restrict__ re) {
    int t = threadIdx.x;
    // coalesced staging: ofb[c] = run start, ofb[CPG+c] = run end (next bin row)
    for (int c = t; c < CPG; c += CT) {
        rs[c] = ofb[c];
        re[c] = ofb[CPG + c];
    }
    __syncthreads();
    int sw = t >> 5, sub = t & 31;
    const int nsw = CT >> 5;       // 16 sub-waves
    int c = sw;
    int2 pcur = make_int2(0, 0);
    int kcur = 0, k1cur = 0;
    if (c < CPG) {
        int cb = c * PCHUNK;
        kcur = cb + rs[c] + sub;
        k1cur = cb + re[c];
        if (kcur < k1cur) pcur = pairsg[kcur];
    }
    while (c < CPG) {
        int cn = c + nsw;
        int2 pnext = make_int2(0, 0);
        int knext = 0, k1next = 0;
        if (cn < CPG) {
            int cb = cn * PCHUNK;
            knext = cb + rs[cn] + sub;
            k1next = cb + re[cn];
            if (knext < k1next) pnext = pairsg[knext];  // prefetch
        }
        if (kcur < k1cur) {
            conv_edge_body(a2g, we, bb, W2, pcur, a1s, acc);
            for (int k = kcur + 32; k < k1cur; k += 32)
                conv_edge_body(a2g, we, bb, W2, pairsg[k], a1s, acc);
        }
        c = cn; kcur = knext; k1cur = k1next; pcur = pnext;
    }
}

// conv + next-layer precompute epilogue (h never hits HBM)
__global__ __launch_bounds__(CT) void conv_mid_kernel(
    const float* __restrict__ a1, const float* __restrict__ a2,
    const float* __restrict__ w1e, const float* __restrict__ W2,
    const float* __restrict__ b2,
    const float* __restrict__ nW1, const float* __restrict__ nb1,
    const int* __restrict__ ofs, const int2* __restrict__ pairs,
    float* __restrict__ na1, float* __restrict__ na2,
    int N, int NB, int CPG, int E) {
    __shared__ float a1s[BS * 9];
    __shared__ unsigned int acc[BS * 9];
    __shared__ int rs[CPGMAX];
    __shared__ int re[CPGMAX];
    int b = blockIdx.y;
    int bin = blockIdx.x;
    int n0 = bin << 7;
    int nCnt = min(BS, N - n0);
    int t = threadIdx.x;
    size_t gn0 = ((size_t)b * N + n0) * 8;

    for (int i = t; i < nCnt * 8; i += CT)
        a1s[(i >> 3) * 9 + (i & 7)] = a1[gn0 + i];
    for (int i = t; i < BS * 9; i += CT) acc[i] = 0xFFFFFFFFu;
    float we[8], bb[8];
#pragma unroll
    for (int j = 0; j < 8; ++j) { we[j] = w1e[j]; bb[j] = b2[j]; }
    __syncthreads();

    conv_edges_runs(a2 + (size_t)b * N * 8, we, bb, W2,
                    pairs + (size_t)b * E,
                    ofs + ((size_t)b * (NB + 1) + bin) * CPG,
                    CPG, a1s, acc, rs, re);
    __syncthreads();

    // decode h into a1s (reuse)
    for (int i = t; i < nCnt * 8; i += CT) {
        float v = fmin_decode(acc[(i >> 3) * 9 + (i & 7)]);
        unsigned int u = __float_as_uint(v);
        if ((u & 0x7F800000u) == 0x7F800000u) v = 0.f;
        a1s[(i >> 3) * 9 + (i & 7)] = lrelu(v);
    }
    __syncthreads();

    // next-layer precompute: 2 threads per node (half 0 -> a1', half 1 -> a2')
    int node = t >> 1, half = t & 1;
    if (node < nCnt) {
        float h[8];
#pragma unroll
        for (int j = 0; j < 8; ++j) h[j] = a1s[node * 9 + j];
        float v[8];
#pragma unroll
        for (int j = 0; j < 8; ++j) v[j] = half ? 0.f : nb1[j];
        const float* Wbase = nW1 + (half ? 64 : 0);
#pragma unroll
        for (int k = 0; k < 8; ++k) {
            float hk = h[k];
#pragma unroll
            for (int j = 0; j < 8; ++j) v[j] = fmaf(hk, Wbase[k * 8 + j], v[j]);
        }
        float* dst = (half ? na2 : na1) + gn0 + (size_t)node * 8;
        float4* o = (float4*)dst;
        o[0] = make_float4(v[0], v[1], v[2], v[3]);
        o[1] = make_float4(v[4], v[5], v[6], v[7]);
    }
}

// final conv: epilogue folds h·lw[3:11] into out[b]
__global__ __launch_bounds__(CT) void conv_final_kernel(
    const float* __restrict__ a1, const float* __restrict__ a2,
    const float* __restrict__ w1e, const float* __restrict__ W2,
    const float* __restrict__ b2, const float* __restrict__ lw,
    const int* __restrict__ ofs, const int2* __restrict__ pairs,
    float* __restrict__ out, int N, int NB, int CPG, int E) {
    __shared__ float a1s[BS * 9];
    __shared__ unsigned int acc[BS * 9];
    __shared__ int rs[CPGMAX];
    __shared__ int re[CPGMAX];
    int b = blockIdx.y;
    int bin = blockIdx.x;
    int n0 = bin << 7;
    int nCnt = min(BS, N - n0);
    int t = threadIdx.x;
    size_t gn0 = ((size_t)b * N + n0) * 8;

    for (int i = t; i < nCnt * 8; i += CT)
        a1s[(i >> 3) * 9 + (i & 7)] = a1[gn0 + i];
    for (int i = t; i < BS * 9; i += CT) acc[i] = 0xFFFFFFFFu;
    float we[8], bb[8];
#pragma unroll
    for (int j = 0; j < 8; ++j) { we[j] = w1e[j]; bb[j] = b2[j]; }
    __syncthreads();

    conv_edges_runs(a2 + (size_t)b * N * 8, we, bb, W2,
                    pairs + (size_t)b * E,
                    ofs + ((size_t)b * (NB + 1) + bin) * CPG,
                    CPG, a1s, acc, rs, re);
    __syncthreads();

    float c = 0.f;
    if (t < nCnt) {
#pragma unroll
        for (int j = 0; j < 8; ++j) {
            float v = fmin_decode(acc[t * 9 + j]);
            unsigned int u = __float_as_uint(v);
            if ((u & 0x7F800000u) == 0x7F800000u) v = 0.f;
            c = fmaf(lrelu(v), lw[3 + j], c);
        }
    }
    __syncthreads();
    block_add(c, &out[b]);
}

// ---------------------------------------------------------------------------
// fallback (R3 proven path): per-edge atomic scatter-min
// ---------------------------------------------------------------------------

__global__ __launch_bounds__(256) void node_init_kernel(
    const int* __restrict__ nf, const float* __restrict__ act,
    float* __restrict__ x0, int BN) {
    int tid = blockIdx.x * blockDim.x + threadIdx.x;
    if (tid >= BN) return;
    x0[tid * 3 + 0] = (float)nf[tid * 2 + 0];
    x0[tid * 3 + 1] = (float)nf[tid * 2 + 1];
    x0[tid * 3 + 2] = act[tid];
}

template <int D>
__global__ __launch_bounds__(256) void edge_conv_kernel(
    const float* __restrict__ x, const int* __restrict__ ei,
    const float* __restrict__ ea,
    const float* __restrict__ W1, const float* __restrict__ b1,
    const float* __restrict__ W2, const float* __restrict__ b2,
    unsigned int* __restrict__ agg, int E, int N, int B) {
    int tid = blockIdx.x * blockDim.x + threadIdx.x;
    if (tid >= B * E) return;
    int b = tid / E;
    int e = tid - b * E;
    const int* eb = ei + (size_t)b * 2 * E;
    int s = eb[e];
    int d = eb[E + e];
    const float* xi = x + ((size_t)b * N + d) * D;
    const float* xj = x + ((size_t)b * N + s) * D;
    constexpr int M = 2 * D + 1;
    float m[M];
#pragma unroll
    for (int k = 0; k < D; ++k) { m[k] = xi[k]; m[D + k] = xj[k]; }
    m[2 * D] = ea[(size_t)b * E + e];
    float h1[8];
#pragma unroll
    for (int j = 0; j < 8; ++j) h1[j] = b1[j];
#pragma unroll
    for (int k = 0; k < M; ++k) {
        float mk = m[k];
#pragma unroll
        for (int j = 0; j < 8; ++j) h1[j] = fmaf(mk, W1[k * 8 + j], h1[j]);
    }
#pragma unroll
    for (int j = 0; j < 8; ++j) h1[j] = lrelu(h1[j]);
    float h2[8];
#pragma unroll
    for (int j = 0; j < 8; ++j) h2[j] = b2[j];
#pragma unroll
    for (int k = 0; k < 8; ++k) {
        float hk = h1[k];
#pragma unroll
        for (int j = 0; j < 8; ++j) h2[j] = fmaf(hk, W2[k * 8 + j], h2[j]);
    }
    unsigned int* ag = agg + ((size_t)b * N + d) * 8;
#pragma unroll
    for (int j = 0; j < 8; ++j) atomicMin(&ag[j], fmin_encode(h2[j]));
}

__global__ __launch_bounds__(256) void finalize_kernel(
    unsigned int* __restrict__ agg, int total) {
    int tid = blockIdx.x * blockDim.x + threadIdx.x;
    if (tid >= total) return;
    float v = fmin_decode(agg[tid]);
    unsigned int u = __float_as_uint(v);
    if ((u & 0x7F800000u) == 0x7F800000u) v = 0.f;
    ((float*)agg)[tid] = lrelu(v);
}

__global__ __launch_bounds__(256) void pool_kernel(
    const float* __restrict__ x0, const float* __restrict__ h,
    const float* __restrict__ lw, const float* __restrict__ lb,
    float* __restrict__ out, int N) {
    int b = blockIdx.y;
    int n = blockIdx.x * blockDim.x + threadIdx.x;
    float c = 0.f;
    if (n < N) {
        const float* x = x0 + ((size_t)b * N + n) * 3;
        const float* hh = h + ((size_t)b * N + n) * 8;
        c = x[0] * lw[0] + x[1] * lw[1] + x[2] * lw[2];
#pragma unroll
        for (int k = 0; k < 8; ++k) c = fmaf(hh[k], lw[3 + k], c);
        if (n == 0) c += lb[0];
    }
    block_add(c, &out[b]);
}

// ---------------------------------------------------------------------------

static inline size_t align256(size_t x) { return (x + 255) & ~(size_t)255; }

extern "C" void kernel_launch(void* const* d_in, const int* in_sizes, int n_in,
                              void* d_out, int out_size, void* d_ws, size_t ws_size,
                              hipStream_t stream) {
    const int B = 4;
    const int N = in_sizes[1] / B;            // actions [B,N]
    const int E = in_sizes[2] / (2 * B);      // edge_index [B,2,E]

    const int*   nf  = (const int*)d_in[0];
    const float* act = (const float*)d_in[1];
    const int*   ei  = (const int*)d_in[2];   // int32 (JAX x64 disabled)
    const float* ea  = (const float*)d_in[3];
    const float* c1_W1 = (const float*)d_in[4];
    const float* c1_b1 = (const float*)d_in[5];
    const float* c1_W2 = (const float*)d_in[6];
    const float* c1_b2 = (const float*)d_in[7];
    const float* c2_W1 = (const float*)d_in[8];
    const float* c2_b1 = (const float*)d_in[9];
    const float* c2_W2 = (const float*)d_in[10];
    const float* c2_b2 = (const float*)d_in[11];
    const float* c3_W1 = (const float*)d_in[12];
    const float* c3_b1 = (const float*)d_in[13];
    const float* c3_W2 = (const float*)d_in[14];
    const float* c3_b2 = (const float*)d_in[15];
    const float* lw    = (const float*)d_in[16];
    const float* lb    = (const float*)d_in[17];
    float* out = (float*)d_out;

    const int BN = B * N;
    const int BE = B * E;
    const int NB = (N + BS - 1) / BS;         // buckets per graph
    const int CPG = (E + PCHUNK - 1) / PCHUNK;

    // ---- workspace layout ----
    char* ws = (char*)d_ws;
    size_t off = 0;
    float* a1A  = (float*)(ws + off);  off += align256((size_t)BN * 8 * 4);
    float* a2A  = (float*)(ws + off);  off += align256((size_t)BN * 8 * 4);
    float* a1B  = (float*)(ws + off);  off += align256((size_t)BN * 8 * 4);
    float* a2B  = (float*)(ws + off);  off += align256((size_t)BN * 8 * 4);
    int* ofs    = (int*)(ws + off);    off += align256((size_t)B * (NB + 1) * CPG * 4);
    int2* pairs = (int2*)(ws + off);   off += align256((size_t)BE * 8);
    // fallback extras
    float* x0   = (float*)(ws + off);  off += align256((size_t)BN * 3 * 4);
    const bool useFast = (off <= ws_size) && (NB <= MAXNB) && (CPG <= CPGMAX) &&
                         (N <= 32768);

    hipMemsetAsync(out, 0, (size_t)B * sizeof(float), stream);

    if (useFast) {
        dim3 pgrid(CPG, B);
        dim3 igrid((N + 255) / 256, B);
        dim3 cgrid(NB, B);

        init_pre1_kernel<<<igrid, 256, 0, stream>>>(nf, act, c1_W1, c1_b1,
                                                    lw, lb, a1A, a2A, out, N);
        part_kernel<<<pgrid, PT, 0, stream>>>(ei, ea, pairs, ofs, E, NB, CPG);

        // conv1: a1A/a2A -> (epilogue pre2) a1B/a2B
        conv_mid_kernel<<<cgrid, CT, 0, stream>>>(
            a1A, a2A, c1_W1 + 6 * 8, c1_W2, c1_b2, c2_W1, c2_b1,
            ofs, pairs, a1B, a2B, N, NB, CPG, E);
        // conv2: a1B/a2B -> (epilogue pre3) a1A/a2A
        conv_mid_kernel<<<cgrid, CT, 0, stream>>>(
            a1B, a2B, c2_W1 + 16 * 8, c2_W2, c2_b2, c3_W1, c3_b1,
            ofs, pairs, a1A, a2A, N, NB, CPG, E);
        // conv3: a1A/a2A -> out (pool fold)
        conv_final_kernel<<<cgrid, CT, 0, stream>>>(
            a1A, a2A, c3_W1 + 16 * 8, c3_W2, c3_b2, lw,
            ofs, pairs, out, N, NB, CPG, E);
    } else {
        // ---- fallback: R3 proven atomic path ----
        const int egrid = (BE + 255) / 256;
        const int aggTotal = BN * 8;
        const int agrid = (aggTotal + 255) / 256;
        const size_t aggBytes = (size_t)aggTotal * 4;
        unsigned int* uA = (unsigned int*)a1A;
        unsigned int* uB = (unsigned int*)a1B;

        node_init_kernel<<<(BN + 255) / 256, 256, 0, stream>>>(nf, act, x0, BN);

        hipMemsetAsync(uA, 0xFF, aggBytes, stream);
        edge_conv_kernel<3><<<egrid, 256, 0, stream>>>(
            x0, ei, ea, c1_W1, c1_b1, c1_W2, c1_b2, uA, E, N, B);
        finalize_kernel<<<agrid, 256, 0, stream>>>(uA, aggTotal);

        hipMemsetAsync(uB, 0xFF, aggBytes, stream);
        edge_conv_kernel<8><<<egrid, 256, 0, stream>>>(
            (const float*)uA, ei, ea, c2_W1, c2_b1, c2_W2, c2_b2, uB, E, N, B);
        finalize_kernel<<<agrid, 256, 0, stream>>>(uB, aggTotal);

        hipMemsetAsync(uA, 0xFF, aggBytes, stream);
        edge_conv_kernel<8><<<egrid, 256, 0, stream>>>(
            (const float*)uB, ei, ea, c3_W1, c3_b1, c3_W2, c3_b2, uA, E, N, B);
        finalize_kernel<<<agrid, 256, 0, stream>>>(uA, aggTotal);

        dim3 plgrid((N + 255) / 256, B);
        pool_kernel<<<plgrid, 256, 0, stream>>>(x0, (const float*)uA, lw, lb, out, N);
    }
}

// Round 12
// 221.026 us; speedup vs baseline: 1.0050x; 1.0050x over previous
//
#include <hip/hip_runtime.h>

#define LEAK 0.01f
#define BS 128           // nodes per bucket (dl fits in 7 bits)
#define PCHUNK 4096      // edges per partition chunk (contiguous 32KB pair window)
#define PT 512           // threads for part (8 waves)
#define CT 256           // threads for conv kernels (1256 blocks -> 4.9/CU balance)
#define MAXNB 256        // max buckets per graph (scan: 1 bin/thread; LDS arrays)
#define CPGMAX 256       // max chunks per graph (conv LDS run arrays)

__device__ __forceinline__ float lrelu(float v) {
    return v >= 0.f ? v : LEAK * v;
}

// ---- float <-> orderable-uint encoding for min (inf -> 0xFFFFFFFF) ----
__device__ __forceinline__ unsigned int fmin_encode(float x) {
    unsigned int u = __float_as_uint(x);
    return (u & 0x80000000u) ? ~u : (u | 0x80000000u);
}
__device__ __forceinline__ float fmin_decode(unsigned int k) {
    unsigned int u = (k & 0x80000000u) ? (k ^ 0x80000000u) : ~k;
    return __uint_as_float(u);
}

// block-reduce (any multiple-of-64 block) + one atomicAdd
__device__ __forceinline__ void block_add(float c, float* dst) {
    __shared__ float wsum[8];
#pragma unroll
    for (int off = 32; off > 0; off >>= 1) c += __shfl_down(c, off, 64);
    int lane = threadIdx.x & 63;
    int wave = threadIdx.x >> 6;
    if (lane == 0) wsum[wave] = c;
    __syncthreads();
    if (threadIdx.x == 0) {
        float s = 0.f;
        int nw = blockDim.x >> 6;
        for (int w = 0; w < nw; ++w) s += wsum[w];
        atomicAdd(dst, s);
    }
}

// ---------------------------------------------------------------------------
// fused partition + init/pre1 kernel.
// blocks [0, CPG): one-pass chunk-local partition (LDS hist -> scan ->
//   chunk-major coalesced pair write + bin-major ofs export).
// blocks [CPG, ...): init + layer-1 precompute + x0 pool fold (overlaps part).
// ofs[b][bin][chunk] = run start; run end = ofs[b][bin+1][chunk]
// pair = { src | dl<<16 , ea_bits }
// ---------------------------------------------------------------------------
__global__ __launch_bounds__(PT) void part_init_kernel(
    const int* __restrict__ ei, const float* __restrict__ ea,
    int2* __restrict__ pairs, int* __restrict__ ofs,
    const int* __restrict__ nf, const float* __restrict__ act,
    const float* __restrict__ W1, const float* __restrict__ b1,
    const float* __restrict__ lw, const float* __restrict__ lb,
    float* __restrict__ a1, float* __restrict__ a2, float* __restrict__ out,
    int E, int N, int NB, int CPG) {
    int b = blockIdx.y;
    int t = threadIdx.x;

    if (blockIdx.x >= CPG) {
        // ---- init role: x0 -> a1/a2 (layer 1) + pool contribution ----
        int n = (blockIdx.x - CPG) * PT + t;
        float c = 0.f;
        if (n < N) {
            size_t i = (size_t)b * N + n;
            float x0 = (float)nf[i * 2 + 0];
            float x1 = (float)nf[i * 2 + 1];
            float x2 = act[i];
            float v1[8], v2[8];
#pragma unroll
            for (int j = 0; j < 8; ++j) {
                v1[j] = b1[j] + x0 * W1[0 * 8 + j] + x1 * W1[1 * 8 + j] + x2 * W1[2 * 8 + j];
                v2[j] =         x0 * W1[3 * 8 + j] + x1 * W1[4 * 8 + j] + x2 * W1[5 * 8 + j];
            }
            float4* o1 = (float4*)(a1 + i * 8);
            float4* o2 = (float4*)(a2 + i * 8);
            o1[0] = make_float4(v1[0], v1[1], v1[2], v1[3]);
            o1[1] = make_float4(v1[4], v1[5], v1[6], v1[7]);
            o2[0] = make_float4(v2[0], v2[1], v2[2], v2[3]);
            o2[1] = make_float4(v2[4], v2[5], v2[6], v2[7]);
            c = x0 * lw[0] + x1 * lw[1] + x2 * lw[2];
            if (n == 0) c += lb[0];
        }
        block_add(c, &out[b]);
        return;
    }

    // ---- partition role ----
    __shared__ int lc[MAXNB];        // hist counts, then run starts
    __shared__ int lofs[MAXNB + 1];  // exclusive starts
    __shared__ int ts[PT];           // scan temp
    int c = blockIdx.x;
    for (int i = t; i < NB; i += PT) lc[i] = 0;
    __syncthreads();

    int e0 = c * PCHUNK;
    int end = min(e0 + PCHUNK, E);
    const int* srow = ei + (size_t)b * 2 * E;
    const int* drow = srow + E;

    // phase 1: hist with per-edge rank capture
    int pk[PCHUNK / PT];  // bin | dl<<10 | rank<<17
#pragma unroll
    for (int j = 0; j < PCHUNK / PT; ++j) {
        int e = e0 + j * PT + t;
        int p = -1;
        if (e < end) {
            int d = drow[e];
            int bin = d >> 7;
            int r = atomicAdd(&lc[bin], 1);
            p = bin | ((d & 127) << 10) | (r << 17);
        }
        pk[j] = p;
    }
    __syncthreads();

    // phase 2: exclusive scan over NB bins (thread t owns bin t; NB <= PT)
    int v = (t < NB) ? lc[t] : 0;
    ts[t] = v;
    __syncthreads();
    int incl = v;
    for (int off = 1; off < PT; off <<= 1) {
        int add = (t >= off) ? ts[t - off] : 0;
        __syncthreads();
        incl += add;
        ts[t] = incl;
        __syncthreads();
    }
    if (t < NB) lofs[t] = incl - v;
    if (t == PT - 1) lofs[NB] = incl;  // = end - e0
    __syncthreads();

    // export ofs (bin-major: [b][i][c]) + set run starts
    for (int i = t; i <= NB; i += PT) {
        int w = lofs[i];
        ofs[((size_t)b * (NB + 1) + i) * CPG + c] = w;
        if (i < NB) lc[i] = w;
    }
    __syncthreads();

    // phase 3: coalesced-window pair write (pos = start + rank, no atomics)
    size_t pbase = (size_t)b * E + e0;
#pragma unroll
    for (int j = 0; j < PCHUNK / PT; ++j) {
        int e = e0 + j * PT + t;
        if (e < end) {
            int p = pk[j];
            int bin = p & 1023;
            int dl = (p >> 10) & 127;
            int r = p >> 17;
            int pos = lc[bin] + r;
            pairs[pbase + pos] =
                make_int2(srow[e] | (dl << 16), __float_as_int(ea[(size_t)b * E + e]));
        }
    }
}

// ---------------------------------------------------------------------------
// bucket conv: one block per 128-node bucket; 32-lane sub-wave per run with
// software-pipelined next-chunk pair prefetch; LDS encoded-uint min acc
// ---------------------------------------------------------------------------

__device__ __forceinline__ void conv_edge_body(
    const float* __restrict__ a2g, const float* we, const float* bb,
    const float* __restrict__ W2, int2 p,
    const float* __restrict__ a1s, unsigned int* __restrict__ acc) {
    int srcn = p.x & 0xFFFF;
    int dl = (p.x >> 16) & 127;
    float eav = __int_as_float(p.y);
    const float4* q = (const float4*)(a2g + (size_t)srcn * 8);
    float4 lo = q[0], hi = q[1];
    float h1[8];
    h1[0] = a1s[dl * 9 + 0] + lo.x; h1[1] = a1s[dl * 9 + 1] + lo.y;
    h1[2] = a1s[dl * 9 + 2] + lo.z; h1[3] = a1s[dl * 9 + 3] + lo.w;
    h1[4] = a1s[dl * 9 + 4] + hi.x; h1[5] = a1s[dl * 9 + 5] + hi.y;
    h1[6] = a1s[dl * 9 + 6] + hi.z; h1[7] = a1s[dl * 9 + 7] + hi.w;
#pragma unroll
    for (int j = 0; j < 8; ++j) {
        h1[j] = fmaf(eav, we[j], h1[j]);
        h1[j] = lrelu(h1[j]);
    }
    float h2[8];
#pragma unroll
    for (int j = 0; j < 8; ++j) h2[j] = bb[j];
#pragma unroll
    for (int kk = 0; kk < 8; ++kk) {
        float hk = h1[kk];
#pragma unroll
        for (int j = 0; j < 8; ++j) h2[j] = fmaf(hk, W2[kk * 8 + j], h2[j]);
    }
#pragma unroll
    for (int j = 0; j < 8; ++j)
        atomicMin(&acc[dl * 9 + j], fmin_encode(h2[j]));
}

// iterate this bucket's run in every chunk; prefetch next chunk's pair while
// computing the current one
__device__ __forceinline__ void conv_edges_runs(
    const float* __restrict__ a2g, const float* we, const float* bb,
    const float* __restrict__ W2, const int2* __restrict__ pairsg,
    const int* __restrict__ ofb, int CPG,
    const float* __restrict__ a1s, unsigned int* __restrict__ acc,
    int* __restrict__ rs, int* __restrict__ re) {
    int t = threadIdx.x;
    // coalesced staging: ofb[c] = run start, ofb[CPG+c] = run end (next bin row)
    for (int c = t; c < CPG; c += CT) {
        rs[c] = ofb[c];
        re[c] = ofb[CPG + c];
    }
    __syncthreads();
    int sw = t >> 5, sub = t & 31;
    const int nsw = CT >> 5;       // 8 sub-waves
    int c = sw;
    int2 pcur = make_int2(0, 0);
    int kcur = 0, k1cur = 0;
    if (c < CPG) {
        int cb = c * PCHUNK;
        kcur = cb + rs[c] + sub;
        k1cur = cb + re[c];
        if (kcur < k1cur) pcur = pairsg[kcur];
    }
    while (c < CPG) {
        int cn = c + nsw;
        int2 pnext = make_int2(0, 0);
        int knext = 0, k1next = 0;
        if (cn < CPG) {
            int cb = cn * PCHUNK;
            knext = cb + rs[cn] + sub;
            k1next = cb + re[cn];
            if (knext < k1next) pnext = pairsg[knext];  // prefetch
        }
        if (kcur < k1cur) {
            conv_edge_body(a2g, we, bb, W2, pcur, a1s, acc);
            for (int k = kcur + 32; k < k1cur; k += 32)
                conv_edge_body(a2g, we, bb, W2, pairsg[k], a1s, acc);
        }
        c = cn; kcur = knext; k1cur = k1next; pcur = pnext;
    }
}

// conv + next-layer precompute epilogue (h never hits HBM)
__global__ __launch_bounds__(CT) void conv_mid_kernel(
    const float* __restrict__ a1, const float* __restrict__ a2,
    const float* __restrict__ w1e, const float* __restrict__ W2,
    const float* __restrict__ b2,
    const float* __restrict__ nW1, const float* __restrict__ nb1,
    const int* __restrict__ ofs, const int2* __restrict__ pairs,
    float* __restrict__ na1, float* __restrict__ na2,
    int N, int NB, int CPG, int E) {
    __shared__ float a1s[BS * 9];
    __shared__ unsigned int acc[BS * 9];
    __shared__ int rs[CPGMAX];
    __shared__ int re[CPGMAX];
    int b = blockIdx.y;
    int bin = blockIdx.x;
    int n0 = bin << 7;
    int nCnt = min(BS, N - n0);
    int t = threadIdx.x;
    size_t gn0 = ((size_t)b * N + n0) * 8;

    for (int i = t; i < nCnt * 8; i += CT)
        a1s[(i >> 3) * 9 + (i & 7)] = a1[gn0 + i];
    for (int i = t; i < BS * 9; i += CT) acc[i] = 0xFFFFFFFFu;
    float we[8], bb[8];
#pragma unroll
    for (int j = 0; j < 8; ++j) { we[j] = w1e[j]; bb[j] = b2[j]; }
    __syncthreads();

    conv_edges_runs(a2 + (size_t)b * N * 8, we, bb, W2,
                    pairs + (size_t)b * E,
                    ofs + ((size_t)b * (NB + 1) + bin) * CPG,
                    CPG, a1s, acc, rs, re);
    __syncthreads();

    // decode h into a1s (reuse)
    for (int i = t; i < nCnt * 8; i += CT) {
        float v = fmin_decode(acc[(i >> 3) * 9 + (i & 7)]);
        unsigned int u = __float_as_uint(v);
        if ((u & 0x7F800000u) == 0x7F800000u) v = 0.f;
        a1s[(i >> 3) * 9 + (i & 7)] = lrelu(v);
    }
    __syncthreads();

    // next-layer precompute: each thread does one (node, half); 2 passes
    for (int nh = t; nh < nCnt * 2; nh += CT) {
        int node = nh >> 1, half = nh & 1;
        float h[8];
#pragma unroll
        for (int j = 0; j < 8; ++j) h[j] = a1s[node * 9 + j];
        float v[8];
#pragma unroll
        for (int j = 0; j < 8; ++j) v[j] = half ? 0.f : nb1[j];
        const float* Wbase = nW1 + (half ? 64 : 0);
#pragma unroll
        for (int k = 0; k < 8; ++k) {
            float hk = h[k];
#pragma unroll
            for (int j = 0; j < 8; ++j) v[j] = fmaf(hk, Wbase[k * 8 + j], v[j]);
        }
        float* dst = (half ? na2 : na1) + gn0 + (size_t)node * 8;
        float4* o = (float4*)dst;
        o[0] = make_float4(v[0], v[1], v[2], v[3]);
        o[1] = make_float4(v[4], v[5], v[6], v[7]);
    }
}

// final conv: epilogue folds h·lw[3:11] into out[b]
__global__ __launch_bounds__(CT) void conv_final_kernel(
    const float* __restrict__ a1, const float* __restrict__ a2,
    const float* __restrict__ w1e, const float* __restrict__ W2,
    const float* __restrict__ b2, const float* __restrict__ lw,
    const int* __restrict__ ofs, const int2* __restrict__ pairs,
    float* __restrict__ out, int N, int NB, int CPG, int E) {
    __shared__ float a1s[BS * 9];
    __shared__ unsigned int acc[BS * 9];
    __shared__ int rs[CPGMAX];
    __shared__ int re[CPGMAX];
    int b = blockIdx.y;
    int bin = blockIdx.x;
    int n0 = bin << 7;
    int nCnt = min(BS, N - n0);
    int t = threadIdx.x;
    size_t gn0 = ((size_t)b * N + n0) * 8;

    for (int i = t; i < nCnt * 8; i += CT)
        a1s[(i >> 3) * 9 + (i & 7)] = a1[gn0 + i];
    for (int i = t; i < BS * 9; i += CT) acc[i] = 0xFFFFFFFFu;
    float we[8], bb[8];
#pragma unroll
    for (int j = 0; j < 8; ++j) { we[j] = w1e[j]; bb[j] = b2[j]; }
    __syncthreads();

    conv_edges_runs(a2 + (size_t)b * N * 8, we, bb, W2,
                    pairs + (size_t)b * E,
                    ofs + ((size_t)b * (NB + 1) + bin) * CPG,
                    CPG, a1s, acc, rs, re);
    __syncthreads();

    float c = 0.f;
    if (t < nCnt) {
#pragma unroll
        for (int j = 0; j < 8; ++j) {
            float v = fmin_decode(acc[t * 9 + j]);
            unsigned int u = __float_as_uint(v);
            if ((u & 0x7F800000u) == 0x7F800000u) v = 0.f;
            c = fmaf(lrelu(v), lw[3 + j], c);
        }
    }
    __syncthreads();
    block_add(c, &out[b]);
}

// ---------------------------------------------------------------------------
// fallback (R3 proven path): per-edge atomic scatter-min
// ---------------------------------------------------------------------------

__global__ __launch_bounds__(256) void node_init_kernel(
    const int* __restrict__ nf, const float* __restrict__ act,
    float* __restrict__ x0, int BN) {
    int tid = blockIdx.x * blockDim.x + threadIdx.x;
    if (tid >= BN) return;
    x0[tid * 3 + 0] = (float)nf[tid * 2 + 0];
    x0[tid * 3 + 1] = (float)nf[tid * 2 + 1];
    x0[tid * 3 + 2] = act[tid];
}

template <int D>
__global__ __launch_bounds__(256) void edge_conv_kernel(
    const float* __restrict__ x, const int* __restrict__ ei,
    const float* __restrict__ ea,
    const float* __restrict__ W1, const float* __restrict__ b1,
    const float* __restrict__ W2, const float* __restrict__ b2,
    unsigned int* __restrict__ agg, int E, int N, int B) {
    int tid = blockIdx.x * blockDim.x + threadIdx.x;
    if (tid >= B * E) return;
    int b = tid / E;
    int e = tid - b * E;
    const int* eb = ei + (size_t)b * 2 * E;
    int s = eb[e];
    int d = eb[E + e];
    const float* xi = x + ((size_t)b * N + d) * D;
    const float* xj = x + ((size_t)b * N + s) * D;
    constexpr int M = 2 * D + 1;
    float m[M];
#pragma unroll
    for (int k = 0; k < D; ++k) { m[k] = xi[k]; m[D + k] = xj[k]; }
    m[2 * D] = ea[(size_t)b * E + e];
    float h1[8];
#pragma unroll
    for (int j = 0; j < 8; ++j) h1[j] = b1[j];
#pragma unroll
    for (int k = 0; k < M; ++k) {
        float mk = m[k];
#pragma unroll
        for (int j = 0; j < 8; ++j) h1[j] = fmaf(mk, W1[k * 8 + j], h1[j]);
    }
#pragma unroll
    for (int j = 0; j < 8; ++j) h1[j] = lrelu(h1[j]);
    float h2[8];
#pragma unroll
    for (int j = 0; j < 8; ++j) h2[j] = b2[j];
#pragma unroll
    for (int k = 0; k < 8; ++k) {
        float hk = h1[k];
#pragma unroll
        for (int j = 0; j < 8; ++j) h2[j] = fmaf(hk, W2[k * 8 + j], h2[j]);
    }
    unsigned int* ag = agg + ((size_t)b * N + d) * 8;
#pragma unroll
    for (int j = 0; j < 8; ++j) atomicMin(&ag[j], fmin_encode(h2[j]));
}

__global__ __launch_bounds__(256) void finalize_kernel(
    unsigned int* __restrict__ agg, int total) {
    int tid = blockIdx.x * blockDim.x + threadIdx.x;
    if (tid >= total) return;
    float v = fmin_decode(agg[tid]);
    unsigned int u = __float_as_uint(v);
    if ((u & 0x7F800000u) == 0x7F800000u) v = 0.f;
    ((float*)agg)[tid] = lrelu(v);
}

__global__ __launch_bounds__(256) void pool_kernel(
    const float* __restrict__ x0, const float* __restrict__ h,
    const float* __restrict__ lw, const float* __restrict__ lb,
    float* __restrict__ out, int N) {
    int b = blockIdx.y;
    int n = blockIdx.x * blockDim.x + threadIdx.x;
    float c = 0.f;
    if (n < N) {
        const float* x = x0 + ((size_t)b * N + n) * 3;
        const float* hh = h + ((size_t)b * N + n) * 8;
        c = x[0] * lw[0] + x[1] * lw[1] + x[2] * lw[2];
#pragma unroll
        for (int k = 0; k < 8; ++k) c = fmaf(hh[k], lw[3 + k], c);
        if (n == 0) c += lb[0];
    }
    block_add(c, &out[b]);
}

// ---------------------------------------------------------------------------

static inline size_t align256(size_t x) { return (x + 255) & ~(size_t)255; }

extern "C" void kernel_launch(void* const* d_in, const int* in_sizes, int n_in,
                              void* d_out, int out_size, void* d_ws, size_t ws_size,
                              hipStream_t stream) {
    const int B = 4;
    const int N = in_sizes[1] / B;            // actions [B,N]
    const int E = in_sizes[2] / (2 * B);      // edge_index [B,2,E]

    const int*   nf  = (const int*)d_in[0];
    const float* act = (const float*)d_in[1];
    const int*   ei  = (const int*)d_in[2];   // int32 (JAX x64 disabled)
    const float* ea  = (const float*)d_in[3];
    const float* c1_W1 = (const float*)d_in[4];
    const float* c1_b1 = (const float*)d_in[5];
    const float* c1_W2 = (const float*)d_in[6];
    const float* c1_b2 = (const float*)d_in[7];
    const float* c2_W1 = (const float*)d_in[8];
    const float* c2_b1 = (const float*)d_in[9];
    const float* c2_W2 = (const float*)d_in[10];
    const float* c2_b2 = (const float*)d_in[11];
    const float* c3_W1 = (const float*)d_in[12];
    const float* c3_b1 = (const float*)d_in[13];
    const float* c3_W2 = (const float*)d_in[14];
    const float* c3_b2 = (const float*)d_in[15];
    const float* lw    = (const float*)d_in[16];
    const float* lb    = (const float*)d_in[17];
    float* out = (float*)d_out;

    const int BN = B * N;
    const int BE = B * E;
    const int NB = (N + BS - 1) / BS;         // buckets per graph
    const int CPG = (E + PCHUNK - 1) / PCHUNK;

    // ---- workspace layout ----
    char* ws = (char*)d_ws;
    size_t off = 0;
    float* a1A  = (float*)(ws + off);  off += align256((size_t)BN * 8 * 4);
    float* a2A  = (float*)(ws + off);  off += align256((size_t)BN * 8 * 4);
    float* a1B  = (float*)(ws + off);  off += align256((size_t)BN * 8 * 4);
    float* a2B  = (float*)(ws + off);  off += align256((size_t)BN * 8 * 4);
    int* ofs    = (int*)(ws + off);    off += align256((size_t)B * (NB + 1) * CPG * 4);
    int2* pairs = (int2*)(ws + off);   off += align256((size_t)BE * 8);
    // fallback extras
    float* x0   = (float*)(ws + off);  off += align256((size_t)BN * 3 * 4);
    const bool useFast = (off <= ws_size) && (NB <= MAXNB) && (CPG <= CPGMAX) &&
                         (N <= 32768);

    hipMemsetAsync(out, 0, (size_t)B * sizeof(float), stream);

    if (useFast) {
        const int initBlocks = (N + PT - 1) / PT;
        dim3 pgrid(CPG + initBlocks, B);
        dim3 cgrid(NB, B);

        part_init_kernel<<<pgrid, PT, 0, stream>>>(
            ei, ea, pairs, ofs, nf, act, c1_W1, c1_b1, lw, lb,
            a1A, a2A, out, E, N, NB, CPG);

        // conv1: a1A/a2A -> (epilogue pre2) a1B/a2B
        conv_mid_kernel<<<cgrid, CT, 0, stream>>>(
            a1A, a2A, c1_W1 + 6 * 8, c1_W2, c1_b2, c2_W1, c2_b1,
            ofs, pairs, a1B, a2B, N, NB, CPG, E);
        // conv2: a1B/a2B -> (epilogue pre3) a1A/a2A
        conv_mid_kernel<<<cgrid, CT, 0, stream>>>(
            a1B, a2B, c2_W1 + 16 * 8, c2_W2, c2_b2, c3_W1, c3_b1,
            ofs, pairs, a1A, a2A, N, NB, CPG, E);
        // conv3: a1A/a2A -> out (pool fold)
        conv_final_kernel<<<cgrid, CT, 0, stream>>>(
            a1A, a2A, c3_W1 + 16 * 8, c3_W2, c3_b2, lw,
            ofs, pairs, out, N, NB, CPG, E);
    } else {
        // ---- fallback: R3 proven atomic path ----
        const int egrid = (BE + 255) / 256;
        const int aggTotal = BN * 8;
        const int agrid = (aggTotal + 255) / 256;
        const size_t aggBytes = (size_t)aggTotal * 4;
        unsigned int* uA = (unsigned int*)a1A;
        unsigned int* uB = (unsigned int*)a1B;

        node_init_kernel<<<(BN + 255) / 256, 256, 0, stream>>>(nf, act, x0, BN);

        hipMemsetAsync(uA, 0xFF, aggBytes, stream);
        edge_conv_kernel<3><<<egrid, 256, 0, stream>>>(
            x0, ei, ea, c1_W1, c1_b1, c1_W2, c1_b2, uA, E, N, B);
        finalize_kernel<<<agrid, 256, 0, stream>>>(uA, aggTotal);

        hipMemsetAsync(uB, 0xFF, aggBytes, stream);
        edge_conv_kernel<8><<<egrid, 256, 0, stream>>>(
            (const float*)uA, ei, ea, c2_W1, c2_b1, c2_W2, c2_b2, uB, E, N, B);
        finalize_kernel<<<agrid, 256, 0, stream>>>(uB, aggTotal);

        hipMemsetAsync(uA, 0xFF, aggBytes, stream);
        edge_conv_kernel<8><<<egrid, 256, 0, stream>>>(
            (const float*)uB, ei, ea, c3_W1, c3_b1, c3_W2, c3_b2, uA, E, N, B);
        finalize_kernel<<<agrid, 256, 0, stream>>>(uA, aggTotal);

        dim3 plgrid((N + 255) / 256, B);
        pool_kernel<<<plgrid, 256, 0, stream>>>(x0, (const float*)uA, lw, lb, out, N);
    }
}

// Round 13
// 219.699 us; speedup vs baseline: 1.0110x; 1.0060x over previous
//
#include <hip/hip_runtime.h>

#define LEAK 0.01f
#define BS 128           // nodes per bucket (dl fits in 7 bits)
#define PCHUNK 4096      // edges per partition chunk (contiguous 32KB pair window)
#define PT 512           // threads for part (8 waves)
#define CT 512           // threads for conv kernels
#define MAXNB 256        // max buckets per graph (scan: 1 bin/thread; LDS arrays)
#define CPGMAX 256       // max chunks per graph (conv LDS run arrays)

__device__ __forceinline__ float lrelu(float v) {
    return v >= 0.f ? v : LEAK * v;
}

// ---- float <-> orderable-uint encoding for min (inf -> 0xFFFFFFFF) ----
__device__ __forceinline__ unsigned int fmin_encode(float x) {
    unsigned int u = __float_as_uint(x);
    return (u & 0x80000000u) ? ~u : (u | 0x80000000u);
}
__device__ __forceinline__ float fmin_decode(unsigned int k) {
    unsigned int u = (k & 0x80000000u) ? (k ^ 0x80000000u) : ~k;
    return __uint_as_float(u);
}

// bf16 pack (RNE) / unpack
__device__ __forceinline__ unsigned int bf16_rne(float f) {
    unsigned int u = __float_as_uint(f);
    return (u + 0x7FFFu + ((u >> 16) & 1u)) >> 16;
}

// block-reduce (any multiple-of-64 block) + one atomicAdd
__device__ __forceinline__ void block_add(float c, float* dst) {
    __shared__ float wsum[8];
#pragma unroll
    for (int off = 32; off > 0; off >>= 1) c += __shfl_down(c, off, 64);
    int lane = threadIdx.x & 63;
    int wave = threadIdx.x >> 6;
    if (lane == 0) wsum[wave] = c;
    __syncthreads();
    if (threadIdx.x == 0) {
        float s = 0.f;
        int nw = blockDim.x >> 6;
        for (int w = 0; w < nw; ++w) s += wsum[w];
        atomicAdd(dst, s);
    }
}

// ---------------------------------------------------------------------------
// fused partition + init/pre1 kernel.
// blocks [0, CPG): one-pass chunk-local partition (LDS hist -> scan ->
//   chunk-major coalesced pair write + bin-major ofs export).
// blocks [CPG, ...): init + layer-1 precompute (a2 in bf16x8!) + x0 pool fold.
// ofs[b][bin][chunk] = run start; run end = ofs[b][bin+1][chunk]
// pair = { src | dl<<16 , ea_bits }
// ---------------------------------------------------------------------------
__global__ __launch_bounds__(PT) void part_init_kernel(
    const int* __restrict__ ei, const float* __restrict__ ea,
    int2* __restrict__ pairs, int* __restrict__ ofs,
    const int* __restrict__ nf, const float* __restrict__ act,
    const float* __restrict__ W1, const float* __restrict__ b1,
    const float* __restrict__ lw, const float* __restrict__ lb,
    float* __restrict__ a1, unsigned short* __restrict__ a2,
    float* __restrict__ out, int E, int N, int NB, int CPG) {
    int b = blockIdx.y;
    int t = threadIdx.x;

    if (blockIdx.x >= CPG) {
        // ---- init role: x0 -> a1 (fp32) / a2 (bf16) + pool contribution ----
        int n = (blockIdx.x - CPG) * PT + t;
        float c = 0.f;
        if (n < N) {
            size_t i = (size_t)b * N + n;
            float x0 = (float)nf[i * 2 + 0];
            float x1 = (float)nf[i * 2 + 1];
            float x2 = act[i];
            float v1[8], v2[8];
#pragma unroll
            for (int j = 0; j < 8; ++j) {
                v1[j] = b1[j] + x0 * W1[0 * 8 + j] + x1 * W1[1 * 8 + j] + x2 * W1[2 * 8 + j];
                v2[j] =         x0 * W1[3 * 8 + j] + x1 * W1[4 * 8 + j] + x2 * W1[5 * 8 + j];
            }
            float4* o1 = (float4*)(a1 + i * 8);
            o1[0] = make_float4(v1[0], v1[1], v1[2], v1[3]);
            o1[1] = make_float4(v1[4], v1[5], v1[6], v1[7]);
            unsigned int w[4];
#pragma unroll
            for (int q = 0; q < 4; ++q)
                w[q] = bf16_rne(v2[2 * q]) | (bf16_rne(v2[2 * q + 1]) << 16);
            *(int4*)(a2 + i * 8) = make_int4(w[0], w[1], w[2], w[3]);
            c = x0 * lw[0] + x1 * lw[1] + x2 * lw[2];
            if (n == 0) c += lb[0];
        }
        block_add(c, &out[b]);
        return;
    }

    // ---- partition role ----
    __shared__ int lc[MAXNB];        // hist counts, then run starts
    __shared__ int lofs[MAXNB + 1];  // exclusive starts
    __shared__ int ts[PT];           // scan temp
    int c = blockIdx.x;
    for (int i = t; i < NB; i += PT) lc[i] = 0;
    __syncthreads();

    int e0 = c * PCHUNK;
    int end = min(e0 + PCHUNK, E);
    const int* srow = ei + (size_t)b * 2 * E;
    const int* drow = srow + E;

    // phase 1: hist with per-edge rank capture
    int pk[PCHUNK / PT];  // bin | dl<<10 | rank<<17
#pragma unroll
    for (int j = 0; j < PCHUNK / PT; ++j) {
        int e = e0 + j * PT + t;
        int p = -1;
        if (e < end) {
            int d = drow[e];
            int bin = d >> 7;
            int r = atomicAdd(&lc[bin], 1);
            p = bin | ((d & 127) << 10) | (r << 17);
        }
        pk[j] = p;
    }
    __syncthreads();

    // phase 2: exclusive scan over NB bins (thread t owns bin t; NB <= PT)
    int v = (t < NB) ? lc[t] : 0;
    ts[t] = v;
    __syncthreads();
    int incl = v;
    for (int off = 1; off < PT; off <<= 1) {
        int add = (t >= off) ? ts[t - off] : 0;
        __syncthreads();
        incl += add;
        ts[t] = incl;
        __syncthreads();
    }
    if (t < NB) lofs[t] = incl - v;
    if (t == PT - 1) lofs[NB] = incl;  // = end - e0
    __syncthreads();

    // export ofs (bin-major: [b][i][c]) + set run starts
    for (int i = t; i <= NB; i += PT) {
        int w = lofs[i];
        ofs[((size_t)b * (NB + 1) + i) * CPG + c] = w;
        if (i < NB) lc[i] = w;
    }
    __syncthreads();

    // phase 3: coalesced-window pair write (pos = start + rank, no atomics)
    size_t pbase = (size_t)b * E + e0;
#pragma unroll
    for (int j = 0; j < PCHUNK / PT; ++j) {
        int e = e0 + j * PT + t;
        if (e < end) {
            int p = pk[j];
            int bin = p & 1023;
            int dl = (p >> 10) & 127;
            int r = p >> 17;
            int pos = lc[bin] + r;
            pairs[pbase + pos] =
                make_int2(srow[e] | (dl << 16), __float_as_int(ea[(size_t)b * E + e]));
        }
    }
}

// ---------------------------------------------------------------------------
// bucket conv: one block per 128-node bucket; 32-lane sub-wave per run with
// software-pipelined next-chunk pair+a2 prefetch; a2 rows are bf16x8 (16 B,
// ONE divergent load per edge); LDS encoded-uint min accumulator
// ---------------------------------------------------------------------------

__device__ __forceinline__ void conv_edge_compute(
    const float* we, const float* bb, const float* __restrict__ W2,
    int2 p, int4 raw, const float* __restrict__ a1s,
    unsigned int* __restrict__ acc) {
    int dl = (p.x >> 16) & 127;
    float eav = __int_as_float(p.y);
    unsigned int wq[4] = {(unsigned int)raw.x, (unsigned int)raw.y,
                          (unsigned int)raw.z, (unsigned int)raw.w};
    float a2v[8];
#pragma unroll
    for (int q = 0; q < 4; ++q) {
        a2v[2 * q]     = __uint_as_float(wq[q] << 16);
        a2v[2 * q + 1] = __uint_as_float(wq[q] & 0xFFFF0000u);
    }
    float h1[8];
#pragma unroll
    for (int j = 0; j < 8; ++j) {
        h1[j] = a1s[dl * 9 + j] + a2v[j];
        h1[j] = fmaf(eav, we[j], h1[j]);
        h1[j] = lrelu(h1[j]);
    }
    float h2[8];
#pragma unroll
    for (int j = 0; j < 8; ++j) h2[j] = bb[j];
#pragma unroll
    for (int kk = 0; kk < 8; ++kk) {
        float hk = h1[kk];
#pragma unroll
        for (int j = 0; j < 8; ++j) h2[j] = fmaf(hk, W2[kk * 8 + j], h2[j]);
    }
#pragma unroll
    for (int j = 0; j < 8; ++j)
        atomicMin(&acc[dl * 9 + j], fmin_encode(h2[j]));
}

// iterate this bucket's run in every chunk; prefetch next chunk's pair AND a2
__device__ __forceinline__ void conv_edges_runs(
    const unsigned short* __restrict__ a2g, const float* we, const float* bb,
    const float* __restrict__ W2, const int2* __restrict__ pairsg,
    const int* __restrict__ ofb, int CPG,
    const float* __restrict__ a1s, unsigned int* __restrict__ acc,
    int* __restrict__ rs, int* __restrict__ re) {
    int t = threadIdx.x;
    // coalesced staging: ofb[c] = run start, ofb[CPG+c] = run end (next bin row)
    for (int c = t; c < CPG; c += CT) {
        rs[c] = ofb[c];
        re[c] = ofb[CPG + c];
    }
    __syncthreads();
    int sw = t >> 5, sub = t & 31;
    const int nsw = CT >> 5;       // 16 sub-waves
    int c = sw;
    int2 pcur = make_int2(0, 0);
    int4 vcur = make_int4(0, 0, 0, 0);
    int kcur = 0, k1cur = 0;
    bool haveCur = false;
    if (c < CPG) {
        int cb = c * PCHUNK;
        kcur = cb + rs[c] + sub;
        k1cur = cb + re[c];
        if (kcur < k1cur) {
            pcur = pairsg[kcur];
            vcur = *(const int4*)(a2g + (size_t)(pcur.x & 0xFFFF) * 8);
            haveCur = true;
        }
    }
    while (c < CPG) {
        int cn = c + nsw;
        int2 pnext = make_int2(0, 0);
        int4 vnext = make_int4(0, 0, 0, 0);
        int knext = 0, k1next = 0;
        bool haveNext = false;
        if (cn < CPG) {
            int cb = cn * PCHUNK;
            knext = cb + rs[cn] + sub;
            k1next = cb + re[cn];
            if (knext < k1next) {
                pnext = pairsg[knext];
                vnext = *(const int4*)(a2g + (size_t)(pnext.x & 0xFFFF) * 8);
                haveNext = true;
            }
        }
        if (haveCur) {
            conv_edge_compute(we, bb, W2, pcur, vcur, a1s, acc);
            for (int k = kcur + 32; k < k1cur; k += 32) {
                int2 p = pairsg[k];
                int4 v = *(const int4*)(a2g + (size_t)(p.x & 0xFFFF) * 8);
                conv_edge_compute(we, bb, W2, p, v, a1s, acc);
            }
        }
        c = cn; pcur = pnext; vcur = vnext; kcur = knext; k1cur = k1next;
        haveCur = haveNext;
    }
}

// conv + next-layer precompute epilogue (h never hits HBM; na2 in bf16)
__global__ __launch_bounds__(CT) void conv_mid_kernel(
    const float* __restrict__ a1, const unsigned short* __restrict__ a2,
    const float* __restrict__ w1e, const float* __restrict__ W2,
    const float* __restrict__ b2,
    const float* __restrict__ nW1, const float* __restrict__ nb1,
    const int* __restrict__ ofs, const int2* __restrict__ pairs,
    float* __restrict__ na1, unsigned short* __restrict__ na2,
    int N, int NB, int CPG, int E) {
    __shared__ float a1s[BS * 9];
    __shared__ unsigned int acc[BS * 9];
    __shared__ int rs[CPGMAX];
    __shared__ int re[CPGMAX];
    int b = blockIdx.y;
    int bin = blockIdx.x;
    int n0 = bin << 7;
    int nCnt = min(BS, N - n0);
    int t = threadIdx.x;
    size_t node0 = (size_t)b * N + n0;

    for (int i = t; i < nCnt * 8; i += CT)
        a1s[(i >> 3) * 9 + (i & 7)] = a1[node0 * 8 + i];
    for (int i = t; i < BS * 9; i += CT) acc[i] = 0xFFFFFFFFu;
    float we[8], bb[8];
#pragma unroll
    for (int j = 0; j < 8; ++j) { we[j] = w1e[j]; bb[j] = b2[j]; }
    __syncthreads();

    conv_edges_runs(a2 + (size_t)b * N * 8, we, bb, W2,
                    pairs + (size_t)b * E,
                    ofs + ((size_t)b * (NB + 1) + bin) * CPG,
                    CPG, a1s, acc, rs, re);
    __syncthreads();

    // decode h into a1s (reuse)
    for (int i = t; i < nCnt * 8; i += CT) {
        float v = fmin_decode(acc[(i >> 3) * 9 + (i & 7)]);
        unsigned int u = __float_as_uint(v);
        if ((u & 0x7F800000u) == 0x7F800000u) v = 0.f;
        a1s[(i >> 3) * 9 + (i & 7)] = lrelu(v);
    }
    __syncthreads();

    // next-layer precompute: (node, half) pairs; half0 -> na1 fp32, half1 -> na2 bf16
    for (int nh = t; nh < nCnt * 2; nh += CT) {
        int node = nh >> 1, half = nh & 1;
        float h[8];
#pragma unroll
        for (int j = 0; j < 8; ++j) h[j] = a1s[node * 9 + j];
        float v[8];
#pragma unroll
        for (int j = 0; j < 8; ++j) v[j] = half ? 0.f : nb1[j];
        const float* Wbase = nW1 + (half ? 64 : 0);
#pragma unroll
        for (int k = 0; k < 8; ++k) {
            float hk = h[k];
#pragma unroll
            for (int j = 0; j < 8; ++j) v[j] = fmaf(hk, Wbase[k * 8 + j], v[j]);
        }
        if (half) {
            unsigned int w[4];
#pragma unroll
            for (int q = 0; q < 4; ++q)
                w[q] = bf16_rne(v[2 * q]) | (bf16_rne(v[2 * q + 1]) << 16);
            *(int4*)(na2 + (node0 + node) * 8) = make_int4(w[0], w[1], w[2], w[3]);
        } else {
            float4* o = (float4*)(na1 + (node0 + node) * 8);
            o[0] = make_float4(v[0], v[1], v[2], v[3]);
            o[1] = make_float4(v[4], v[5], v[6], v[7]);
        }
    }
}

// final conv: epilogue folds h·lw[3:11] into out[b]
__global__ __launch_bounds__(CT) void conv_final_kernel(
    const float* __restrict__ a1, const unsigned short* __restrict__ a2,
    const float* __restrict__ w1e, const float* __restrict__ W2,
    const float* __restrict__ b2, const float* __restrict__ lw,
    const int* __restrict__ ofs, const int2* __restrict__ pairs,
    float* __restrict__ out, int N, int NB, int CPG, int E) {
    __shared__ float a1s[BS * 9];
    __shared__ unsigned int acc[BS * 9];
    __shared__ int rs[CPGMAX];
    __shared__ int re[CPGMAX];
    int b = blockIdx.y;
    int bin = blockIdx.x;
    int n0 = bin << 7;
    int nCnt = min(BS, N - n0);
    int t = threadIdx.x;
    size_t node0 = (size_t)b * N + n0;

    for (int i = t; i < nCnt * 8; i += CT)
        a1s[(i >> 3) * 9 + (i & 7)] = a1[node0 * 8 + i];
    for (int i = t; i < BS * 9; i += CT) acc[i] = 0xFFFFFFFFu;
    float we[8], bb[8];
#pragma unroll
    for (int j = 0; j < 8; ++j) { we[j] = w1e[j]; bb[j] = b2[j]; }
    __syncthreads();

    conv_edges_runs(a2 + (size_t)b * N * 8, we, bb, W2,
                    pairs + (size_t)b * E,
                    ofs + ((size_t)b * (NB + 1) + bin) * CPG,
                    CPG, a1s, acc, rs, re);
    __syncthreads();

    float c = 0.f;
    if (t < nCnt) {
#pragma unroll
        for (int j = 0; j < 8; ++j) {
            float v = fmin_decode(acc[t * 9 + j]);
            unsigned int u = __float_as_uint(v);
            if ((u & 0x7F800000u) == 0x7F800000u) v = 0.f;
            c = fmaf(lrelu(v), lw[3 + j], c);
        }
    }
    __syncthreads();
    block_add(c, &out[b]);
}

// ---------------------------------------------------------------------------
// fallback (R3 proven path): per-edge atomic scatter-min
// ---------------------------------------------------------------------------

__global__ __launch_bounds__(256) void node_init_kernel(
    const int* __restrict__ nf, const float* __restrict__ act,
    float* __restrict__ x0, int BN) {
    int tid = blockIdx.x * blockDim.x + threadIdx.x;
    if (tid >= BN) return;
    x0[tid * 3 + 0] = (float)nf[tid * 2 + 0];
    x0[tid * 3 + 1] = (float)nf[tid * 2 + 1];
    x0[tid * 3 + 2] = act[tid];
}

template <int D>
__global__ __launch_bounds__(256) void edge_conv_kernel(
    const float* __restrict__ x, const int* __restrict__ ei,
    const float* __restrict__ ea,
    const float* __restrict__ W1, const float* __restrict__ b1,
    const float* __restrict__ W2, const float* __restrict__ b2,
    unsigned int* __restrict__ agg, int E, int N, int B) {
    int tid = blockIdx.x * blockDim.x + threadIdx.x;
    if (tid >= B * E) return;
    int b = tid / E;
    int e = tid - b * E;
    const int* eb = ei + (size_t)b * 2 * E;
    int s = eb[e];
    int d = eb[E + e];
    const float* xi = x + ((size_t)b * N + d) * D;
    const float* xj = x + ((size_t)b * N + s) * D;
    constexpr int M = 2 * D + 1;
    float m[M];
#pragma unroll
    for (int k = 0; k < D; ++k) { m[k] = xi[k]; m[D + k] = xj[k]; }
    m[2 * D] = ea[(size_t)b * E + e];
    float h1[8];
#pragma unroll
    for (int j = 0; j < 8; ++j) h1[j] = b1[j];
#pragma unroll
    for (int k = 0; k < M; ++k) {
        float mk = m[k];
#pragma unroll
        for (int j = 0; j < 8; ++j) h1[j] = fmaf(mk, W1[k * 8 + j], h1[j]);
    }
#pragma unroll
    for (int j = 0; j < 8; ++j) h1[j] = lrelu(h1[j]);
    float h2[8];
#pragma unroll
    for (int j = 0; j < 8; ++j) h2[j] = b2[j];
#pragma unroll
    for (int k = 0; k < 8; ++k) {
        float hk = h1[k];
#pragma unroll
        for (int j = 0; j < 8; ++j) h2[j] = fmaf(hk, W2[k * 8 + j], h2[j]);
    }
    unsigned int* ag = agg + ((size_t)b * N + d) * 8;
#pragma unroll
    for (int j = 0; j < 8; ++j) atomicMin(&ag[j], fmin_encode(h2[j]));
}

__global__ __launch_bounds__(256) void finalize_kernel(
    unsigned int* __restrict__ agg, int total) {
    int tid = blockIdx.x * blockDim.x + threadIdx.x;
    if (tid >= total) return;
    float v = fmin_decode(agg[tid]);
    unsigned int u = __float_as_uint(v);
    if ((u & 0x7F800000u) == 0x7F800000u) v = 0.f;
    ((float*)agg)[tid] = lrelu(v);
}

__global__ __launch_bounds__(256) void pool_kernel(
    const float* __restrict__ x0, const float* __restrict__ h,
    const float* __restrict__ lw, const float* __restrict__ lb,
    float* __restrict__ out, int N) {
    int b = blockIdx.y;
    int n = blockIdx.x * blockDim.x + threadIdx.x;
    float c = 0.f;
    if (n < N) {
        const float* x = x0 + ((size_t)b * N + n) * 3;
        const float* hh = h + ((size_t)b * N + n) * 8;
        c = x[0] * lw[0] + x[1] * lw[1] + x[2] * lw[2];
#pragma unroll
        for (int k = 0; k < 8; ++k) c = fmaf(hh[k], lw[3 + k], c);
        if (n == 0) c += lb[0];
    }
    block_add(c, &out[b]);
}

// ---------------------------------------------------------------------------

static inline size_t align256(size_t x) { return (x + 255) & ~(size_t)255; }

extern "C" void kernel_launch(void* const* d_in, const int* in_sizes, int n_in,
                              void* d_out, int out_size, void* d_ws, size_t ws_size,
                              hipStream_t stream) {
    const int B = 4;
    const int N = in_sizes[1] / B;            // actions [B,N]
    const int E = in_sizes[2] / (2 * B);      // edge_index [B,2,E]

    const int*   nf  = (const int*)d_in[0];
    const float* act = (const float*)d_in[1];
    const int*   ei  = (const int*)d_in[2];   // int32 (JAX x64 disabled)
    const float* ea  = (const float*)d_in[3];
    const float* c1_W1 = (const float*)d_in[4];
    const float* c1_b1 = (const float*)d_in[5];
    const float* c1_W2 = (const float*)d_in[6];
    const float* c1_b2 = (const float*)d_in[7];
    const float* c2_W1 = (const float*)d_in[8];
    const float* c2_b1 = (const float*)d_in[9];
    const float* c2_W2 = (const float*)d_in[10];
    const float* c2_b2 = (const float*)d_in[11];
    const float* c3_W1 = (const float*)d_in[12];
    const float* c3_b1 = (const float*)d_in[13];
    const float* c3_W2 = (const float*)d_in[14];
    const float* c3_b2 = (const float*)d_in[15];
    const float* lw    = (const float*)d_in[16];
    const float* lb    = (const float*)d_in[17];
    float* out = (float*)d_out;

    const int BN = B * N;
    const int BE = B * E;
    const int NB = (N + BS - 1) / BS;         // buckets per graph
    const int CPG = (E + PCHUNK - 1) / PCHUNK;

    // ---- workspace layout ----
    char* ws = (char*)d_ws;
    size_t off = 0;
    float* a1A = (float*)(ws + off);           off += align256((size_t)BN * 8 * 4);
    float* a1B = (float*)(ws + off);           off += align256((size_t)BN * 8 * 4);
    unsigned short* a2A = (unsigned short*)(ws + off); off += align256((size_t)BN * 8 * 2);
    unsigned short* a2B = (unsigned short*)(ws + off); off += align256((size_t)BN * 8 * 2);
    int* ofs    = (int*)(ws + off);    off += align256((size_t)B * (NB + 1) * CPG * 4);
    int2* pairs = (int2*)(ws + off);   off += align256((size_t)BE * 8);
    // fallback extras
    float* x0   = (float*)(ws + off);  off += align256((size_t)BN * 3 * 4);
    const bool useFast = (off <= ws_size) && (NB <= MAXNB) && (CPG <= CPGMAX) &&
                         (N <= 32768);

    hipMemsetAsync(out, 0, (size_t)B * sizeof(float), stream);

    if (useFast) {
        const int initBlocks = (N + PT - 1) / PT;
        dim3 pgrid(CPG + initBlocks, B);
        dim3 cgrid(NB, B);

        part_init_kernel<<<pgrid, PT, 0, stream>>>(
            ei, ea, pairs, ofs, nf, act, c1_W1, c1_b1, lw, lb,
            a1A, a2A, out, E, N, NB, CPG);

        // conv1: a1A/a2A -> (epilogue pre2) a1B/a2B
        conv_mid_kernel<<<cgrid, CT, 0, stream>>>(
            a1A, a2A, c1_W1 + 6 * 8, c1_W2, c1_b2, c2_W1, c2_b1,
            ofs, pairs, a1B, a2B, N, NB, CPG, E);
        // conv2: a1B/a2B -> (epilogue pre3) a1A/a2A
        conv_mid_kernel<<<cgrid, CT, 0, stream>>>(
            a1B, a2B, c2_W1 + 16 * 8, c2_W2, c2_b2, c3_W1, c3_b1,
            ofs, pairs, a1A, a2A, N, NB, CPG, E);
        // conv3: a1A/a2A -> out (pool fold)
        conv_final_kernel<<<cgrid, CT, 0, stream>>>(
            a1A, a2A, c3_W1 + 16 * 8, c3_W2, c3_b2, lw,
            ofs, pairs, out, N, NB, CPG, E);
    } else {
        // ---- fallback: R3 proven atomic path ----
        const int egrid = (BE + 255) / 256;
        const int aggTotal = BN * 8;
        const int agrid = (aggTotal + 255) / 256;
        const size_t aggBytes = (size_t)aggTotal * 4;
        unsigned int* uA = (unsigned int*)a1A;
        unsigned int* uB = (unsigned int*)a1B;

        node_init_kernel<<<(BN + 255) / 256, 256, 0, stream>>>(nf, act, x0, BN);

        hipMemsetAsync(uA, 0xFF, aggBytes, stream);
        edge_conv_kernel<3><<<egrid, 256, 0, stream>>>(
            x0, ei, ea, c1_W1, c1_b1, c1_W2, c1_b2, uA, E, N, B);
        finalize_kernel<<<agrid, 256, 0, stream>>>(uA, aggTotal);

        hipMemsetAsync(uB, 0xFF, aggBytes, stream);
        edge_conv_kernel<8><<<egrid, 256, 0, stream>>>(
            (const float*)uA, ei, ea, c2_W1, c2_b1, c2_W2, c2_b2, uB, E, N, B);
        finalize_kernel<<<agrid, 256, 0, stream>>>(uB, aggTotal);

        hipMemsetAsync(uA, 0xFF, aggBytes, stream);
        edge_conv_kernel<8><<<egrid, 256, 0, stream>>>(
            (const float*)uB, ei, ea, c3_W1, c3_b1, c3_W2, c3_b2, uA, E, N, B);
        finalize_kernel<<<agrid, 256, 0, stream>>>(uA, aggTotal);

        dim3 plgrid((N + 255) / 256, B);
        pool_kernel<<<plgrid, 256, 0, stream>>>(x0, (const float*)uA, lw, lb, out, N);
    }
}

// Round 14
// 206.261 us; speedup vs baseline: 1.0769x; 1.0652x over previous
//
#include <hip/hip_runtime.h>
#include <hip/hip_cooperative_groups.h>

namespace cg = cooperative_groups;

#define LEAK 0.01f
#define BS 128           // nodes per bucket (dl fits in 7 bits)
#define PCHUNK 4096      // edges per partition chunk (contiguous 32KB pair window)
#define PT 512           // unified block size
#define CT 512
#define MAXNB 256        // max buckets per graph
#define CPGMAX 256       // max chunks per graph

__device__ __forceinline__ float lrelu(float v) {
    return v >= 0.f ? v : LEAK * v;
}

__device__ __forceinline__ unsigned int fmin_encode(float x) {
    unsigned int u = __float_as_uint(x);
    return (u & 0x80000000u) ? ~u : (u | 0x80000000u);
}
__device__ __forceinline__ float fmin_decode(unsigned int k) {
    unsigned int u = (k & 0x80000000u) ? (k ^ 0x80000000u) : ~k;
    return __uint_as_float(u);
}

__device__ __forceinline__ unsigned int bf16_rne(float f) {
    unsigned int u = __float_as_uint(f);
    return (u + 0x7FFFu + ((u >> 16) & 1u)) >> 16;
}

__device__ __forceinline__ void block_add(float c, float* dst) {
    __shared__ float wsum[8];
#pragma unroll
    for (int off = 32; off > 0; off >>= 1) c += __shfl_down(c, off, 64);
    int lane = threadIdx.x & 63;
    int wave = threadIdx.x >> 6;
    if (lane == 0) wsum[wave] = c;
    __syncthreads();
    if (threadIdx.x == 0) {
        float s = 0.f;
        int nw = blockDim.x >> 6;
        for (int w = 0; w < nw; ++w) s += wsum[w];
        atomicAdd(dst, s);
    }
}

// ---------------------------------------------------------------------------
// phase bodies (shared between mega kernel and standalone fallback kernels)
// ---------------------------------------------------------------------------

__device__ void init_body(
    const int* __restrict__ nf, const float* __restrict__ act,
    const float* __restrict__ W1, const float* __restrict__ b1,
    const float* __restrict__ lw, const float* __restrict__ lb,
    float* __restrict__ a1, unsigned short* __restrict__ a2,
    float* __restrict__ out, int N, int b, int ib) {
    int t = threadIdx.x;
    int n = ib * PT + t;
    float c = 0.f;
    if (n < N) {
        size_t i = (size_t)b * N + n;
        float x0 = (float)nf[i * 2 + 0];
        float x1 = (float)nf[i * 2 + 1];
        float x2 = act[i];
        float v1[8], v2[8];
#pragma unroll
        for (int j = 0; j < 8; ++j) {
            v1[j] = b1[j] + x0 * W1[0 * 8 + j] + x1 * W1[1 * 8 + j] + x2 * W1[2 * 8 + j];
            v2[j] =         x0 * W1[3 * 8 + j] + x1 * W1[4 * 8 + j] + x2 * W1[5 * 8 + j];
        }
        float4* o1 = (float4*)(a1 + i * 8);
        o1[0] = make_float4(v1[0], v1[1], v1[2], v1[3]);
        o1[1] = make_float4(v1[4], v1[5], v1[6], v1[7]);
        unsigned int w[4];
#pragma unroll
        for (int q = 0; q < 4; ++q)
            w[q] = bf16_rne(v2[2 * q]) | (bf16_rne(v2[2 * q + 1]) << 16);
        *(int4*)(a2 + i * 8) = make_int4(w[0], w[1], w[2], w[3]);
        c = x0 * lw[0] + x1 * lw[1] + x2 * lw[2];
        if (n == 0) c += lb[0];
    }
    block_add(c, &out[b]);
}

__device__ void part_body(
    const int* __restrict__ ei, const float* __restrict__ ea,
    int2* __restrict__ pairs, int* __restrict__ ofs,
    int E, int NB, int CPG, int b, int c,
    int* __restrict__ lc, int* __restrict__ lofs, int* __restrict__ ts) {
    int t = threadIdx.x;
    for (int i = t; i < NB; i += PT) lc[i] = 0;
    __syncthreads();

    int e0 = c * PCHUNK;
    int end = min(e0 + PCHUNK, E);
    const int* srow = ei + (size_t)b * 2 * E;
    const int* drow = srow + E;

    int pk[PCHUNK / PT];  // bin | dl<<10 | rank<<17
#pragma unroll
    for (int j = 0; j < PCHUNK / PT; ++j) {
        int e = e0 + j * PT + t;
        int p = -1;
        if (e < end) {
            int d = drow[e];
            int bin = d >> 7;
            int r = atomicAdd(&lc[bin], 1);
            p = bin | ((d & 127) << 10) | (r << 17);
        }
        pk[j] = p;
    }
    __syncthreads();

    int v = (t < NB) ? lc[t] : 0;
    ts[t] = v;
    __syncthreads();
    int incl = v;
    for (int off = 1; off < PT; off <<= 1) {
        int add = (t >= off) ? ts[t - off] : 0;
        __syncthreads();
        incl += add;
        ts[t] = incl;
        __syncthreads();
    }
    if (t < NB) lofs[t] = incl - v;
    if (t == PT - 1) lofs[NB] = incl;
    __syncthreads();

    for (int i = t; i <= NB; i += PT) {
        int w = lofs[i];
        ofs[((size_t)b * (NB + 1) + i) * CPG + c] = w;
        if (i < NB) lc[i] = w;
    }
    __syncthreads();

    size_t pbase = (size_t)b * E + e0;
#pragma unroll
    for (int j = 0; j < PCHUNK / PT; ++j) {
        int e = e0 + j * PT + t;
        if (e < end) {
            int p = pk[j];
            int bin = p & 1023;
            int dl = (p >> 10) & 127;
            int r = p >> 17;
            int pos = lc[bin] + r;
            pairs[pbase + pos] =
                make_int2(srow[e] | (dl << 16), __float_as_int(ea[(size_t)b * E + e]));
        }
    }
}

__device__ __forceinline__ void conv_edge_compute(
    const float* we, const float* bb, const float* __restrict__ W2,
    int2 p, int4 raw, const float* __restrict__ a1s,
    unsigned int* __restrict__ acc) {
    int dl = (p.x >> 16) & 127;
    float eav = __int_as_float(p.y);
    unsigned int wq[4] = {(unsigned int)raw.x, (unsigned int)raw.y,
                          (unsigned int)raw.z, (unsigned int)raw.w};
    float a2v[8];
#pragma unroll
    for (int q = 0; q < 4; ++q) {
        a2v[2 * q]     = __uint_as_float(wq[q] << 16);
        a2v[2 * q + 1] = __uint_as_float(wq[q] & 0xFFFF0000u);
    }
    float h1[8];
#pragma unroll
    for (int j = 0; j < 8; ++j) {
        h1[j] = a1s[dl * 9 + j] + a2v[j];
        h1[j] = fmaf(eav, we[j], h1[j]);
        h1[j] = lrelu(h1[j]);
    }
    float h2[8];
#pragma unroll
    for (int j = 0; j < 8; ++j) h2[j] = bb[j];
#pragma unroll
    for (int kk = 0; kk < 8; ++kk) {
        float hk = h1[kk];
#pragma unroll
        for (int j = 0; j < 8; ++j) h2[j] = fmaf(hk, W2[kk * 8 + j], h2[j]);
    }
#pragma unroll
    for (int j = 0; j < 8; ++j)
        atomicMin(&acc[dl * 9 + j], fmin_encode(h2[j]));
}

__device__ void conv_edges_runs(
    const unsigned short* __restrict__ a2g, const float* we, const float* bb,
    const float* __restrict__ W2, const int2* __restrict__ pairsg,
    const int* __restrict__ ofb, int CPG,
    const float* __restrict__ a1s, unsigned int* __restrict__ acc,
    int* __restrict__ rs, int* __restrict__ re) {
    int t = threadIdx.x;
    for (int c = t; c < CPG; c += CT) {
        rs[c] = ofb[c];
        re[c] = ofb[CPG + c];
    }
    __syncthreads();
    int sw = t >> 5, sub = t & 31;
    const int nsw = CT >> 5;
    for (int c = sw; c < CPG; c += nsw) {
        int cb = c * PCHUNK;
        int k1 = cb + re[c];
        for (int k = cb + rs[c] + sub; k < k1; k += 32) {
            int2 p = pairsg[k];
            int4 v = *(const int4*)(a2g + (size_t)(p.x & 0xFFFF) * 8);
            conv_edge_compute(we, bb, W2, p, v, a1s, acc);
        }
    }
}

__device__ void conv_mid_body(
    const float* __restrict__ a1, const unsigned short* __restrict__ a2,
    const float* __restrict__ w1e, const float* __restrict__ W2,
    const float* __restrict__ b2,
    const float* __restrict__ nW1, const float* __restrict__ nb1,
    const int* __restrict__ ofs, const int2* __restrict__ pairs,
    float* __restrict__ na1, unsigned short* __restrict__ na2,
    int N, int NB, int CPG, int E, int b, int bin,
    float* __restrict__ a1s, unsigned int* __restrict__ acc,
    int* __restrict__ rs, int* __restrict__ re) {
    int n0 = bin << 7;
    int nCnt = min(BS, N - n0);
    int t = threadIdx.x;
    size_t node0 = (size_t)b * N + n0;

    for (int i = t; i < nCnt * 8; i += CT)
        a1s[(i >> 3) * 9 + (i & 7)] = a1[node0 * 8 + i];
    for (int i = t; i < BS * 9; i += CT) acc[i] = 0xFFFFFFFFu;
    float we[8], bb[8];
#pragma unroll
    for (int j = 0; j < 8; ++j) { we[j] = w1e[j]; bb[j] = b2[j]; }
    __syncthreads();

    conv_edges_runs(a2 + (size_t)b * N * 8, we, bb, W2,
                    pairs + (size_t)b * E,
                    ofs + ((size_t)b * (NB + 1) + bin) * CPG,
                    CPG, a1s, acc, rs, re);
    __syncthreads();

    for (int i = t; i < nCnt * 8; i += CT) {
        float v = fmin_decode(acc[(i >> 3) * 9 + (i & 7)]);
        unsigned int u = __float_as_uint(v);
        if ((u & 0x7F800000u) == 0x7F800000u) v = 0.f;
        a1s[(i >> 3) * 9 + (i & 7)] = lrelu(v);
    }
    __syncthreads();

    for (int nh = t; nh < nCnt * 2; nh += CT) {
        int node = nh >> 1, half = nh & 1;
        float h[8];
#pragma unroll
        for (int j = 0; j < 8; ++j) h[j] = a1s[node * 9 + j];
        float v[8];
#pragma unroll
        for (int j = 0; j < 8; ++j) v[j] = half ? 0.f : nb1[j];
        const float* Wbase = nW1 + (half ? 64 : 0);
#pragma unroll
        for (int k = 0; k < 8; ++k) {
            float hk = h[k];
#pragma unroll
            for (int j = 0; j < 8; ++j) v[j] = fmaf(hk, Wbase[k * 8 + j], v[j]);
        }
        if (half) {
            unsigned int w[4];
#pragma unroll
            for (int q = 0; q < 4; ++q)
                w[q] = bf16_rne(v[2 * q]) | (bf16_rne(v[2 * q + 1]) << 16);
            *(int4*)(na2 + (node0 + node) * 8) = make_int4(w[0], w[1], w[2], w[3]);
        } else {
            float4* o = (float4*)(na1 + (node0 + node) * 8);
            o[0] = make_float4(v[0], v[1], v[2], v[3]);
            o[1] = make_float4(v[4], v[5], v[6], v[7]);
        }
    }
    __syncthreads();
}

__device__ void conv_final_body(
    const float* __restrict__ a1, const unsigned short* __restrict__ a2,
    const float* __restrict__ w1e, const float* __restrict__ W2,
    const float* __restrict__ b2, const float* __restrict__ lw,
    const int* __restrict__ ofs, const int2* __restrict__ pairs,
    float* __restrict__ out, int N, int NB, int CPG, int E, int b, int bin,
    float* __restrict__ a1s, unsigned int* __restrict__ acc,
    int* __restrict__ rs, int* __restrict__ re) {
    int n0 = bin << 7;
    int nCnt = min(BS, N - n0);
    int t = threadIdx.x;
    size_t node0 = (size_t)b * N + n0;

    for (int i = t; i < nCnt * 8; i += CT)
        a1s[(i >> 3) * 9 + (i & 7)] = a1[node0 * 8 + i];
    for (int i = t; i < BS * 9; i += CT) acc[i] = 0xFFFFFFFFu;
    float we[8], bb[8];
#pragma unroll
    for (int j = 0; j < 8; ++j) { we[j] = w1e[j]; bb[j] = b2[j]; }
    __syncthreads();

    conv_edges_runs(a2 + (size_t)b * N * 8, we, bb, W2,
                    pairs + (size_t)b * E,
                    ofs + ((size_t)b * (NB + 1) + bin) * CPG,
                    CPG, a1s, acc, rs, re);
    __syncthreads();

    float c = 0.f;
    if (t < nCnt) {
#pragma unroll
        for (int j = 0; j < 8; ++j) {
            float v = fmin_decode(acc[t * 9 + j]);
            unsigned int u = __float_as_uint(v);
            if ((u & 0x7F800000u) == 0x7F800000u) v = 0.f;
            c = fmaf(lrelu(v), lw[3 + j], c);
        }
    }
    __syncthreads();
    block_add(c, &out[b]);
}

// ---------------------------------------------------------------------------
// cooperative mega kernel: part+init | conv1 | conv2 | conv3+pool
// ---------------------------------------------------------------------------

struct MegaParams {
    const int* ei; const float* ea;
    int2* pairs; int* ofs;
    const int* nf; const float* act;
    const float* W11; const float* b11; const float* W21; const float* b21;
    const float* W12; const float* b12; const float* W22; const float* b22;
    const float* W13; const float* b13; const float* W23; const float* b23;
    const float* lw; const float* lb;
    float* a1A; unsigned short* a2A; float* a1B; unsigned short* a2B;
    float* out;
    int E, N, NB, CPG, initBlocks;
};

__global__ __launch_bounds__(512, 8) void mega_kernel(MegaParams P) {
    cg::grid_group grid = cg::this_grid();
    __shared__ int lc[MAXNB];
    __shared__ int lofs[MAXNB + 1];
    __shared__ int ts[PT];
    __shared__ float a1s[BS * 9];
    __shared__ unsigned int acc[BS * 9];
    __shared__ int rs[CPGMAX];
    __shared__ int re[CPGMAX];
    int b = blockIdx.y, bx = blockIdx.x;

    if (bx < P.CPG)
        part_body(P.ei, P.ea, P.pairs, P.ofs, P.E, P.NB, P.CPG, b, bx, lc, lofs, ts);
    else if (bx - P.CPG < P.initBlocks)
        init_body(P.nf, P.act, P.W11, P.b11, P.lw, P.lb, P.a1A, P.a2A, P.out,
                  P.N, b, bx - P.CPG);
    __threadfence();
    grid.sync();
    if (bx < P.NB)
        conv_mid_body(P.a1A, P.a2A, P.W11 + 6 * 8, P.W21, P.b21, P.W12, P.b12,
                      P.ofs, P.pairs, P.a1B, P.a2B, P.N, P.NB, P.CPG, P.E,
                      b, bx, a1s, acc, rs, re);
    __threadfence();
    grid.sync();
    if (bx < P.NB)
        conv_mid_body(P.a1B, P.a2B, P.W12 + 16 * 8, P.W22, P.b22, P.W13, P.b13,
                      P.ofs, P.pairs, P.a1A, P.a2A, P.N, P.NB, P.CPG, P.E,
                      b, bx, a1s, acc, rs, re);
    __threadfence();
    grid.sync();
    if (bx < P.NB)
        conv_final_body(P.a1A, P.a2A, P.W13 + 16 * 8, P.W23, P.b23, P.lw,
                        P.ofs, P.pairs, P.out, P.N, P.NB, P.CPG, P.E,
                        b, bx, a1s, acc, rs, re);
}

// ---------------------------------------------------------------------------
// standalone kernels (non-cooperative fallback, proven R13 path)
// ---------------------------------------------------------------------------

__global__ __launch_bounds__(PT) void part_init_kernel(
    const int* __restrict__ ei, const float* __restrict__ ea,
    int2* __restrict__ pairs, int* __restrict__ ofs,
    const int* __restrict__ nf, const float* __restrict__ act,
    const float* __restrict__ W1, const float* __restrict__ b1,
    const float* __restrict__ lw, const float* __restrict__ lb,
    float* __restrict__ a1, unsigned short* __restrict__ a2,
    float* __restrict__ out, int E, int N, int NB, int CPG) {
    __shared__ int lc[MAXNB];
    __shared__ int lofs[MAXNB + 1];
    __shared__ int ts[PT];
    int b = blockIdx.y;
    if (blockIdx.x >= CPG) {
        init_body(nf, act, W1, b1, lw, lb, a1, a2, out, N, b, blockIdx.x - CPG);
        return;
    }
    part_body(ei, ea, pairs, ofs, E, NB, CPG, b, blockIdx.x, lc, lofs, ts);
}

__global__ __launch_bounds__(CT) void conv_mid_kernel(
    const float* __restrict__ a1, const unsigned short* __restrict__ a2,
    const float* __restrict__ w1e, const float* __restrict__ W2,
    const float* __restrict__ b2,
    const float* __restrict__ nW1, const float* __restrict__ nb1,
    const int* __restrict__ ofs, const int2* __restrict__ pairs,
    float* __restrict__ na1, unsigned short* __restrict__ na2,
    int N, int NB, int CPG, int E) {
    __shared__ float a1s[BS * 9];
    __shared__ unsigned int acc[BS * 9];
    __shared__ int rs[CPGMAX];
    __shared__ int re[CPGMAX];
    conv_mid_body(a1, a2, w1e, W2, b2, nW1, nb1, ofs, pairs, na1, na2,
                  N, NB, CPG, E, blockIdx.y, blockIdx.x, a1s, acc, rs, re);
}

__global__ __launch_bounds__(CT) void conv_final_kernel(
    const float* __restrict__ a1, const unsigned short* __restrict__ a2,
    const float* __restrict__ w1e, const float* __restrict__ W2,
    const float* __restrict__ b2, const float* __restrict__ lw,
    const int* __restrict__ ofs, const int2* __restrict__ pairs,
    float* __restrict__ out, int N, int NB, int CPG, int E) {
    __shared__ float a1s[BS * 9];
    __shared__ unsigned int acc[BS * 9];
    __shared__ int rs[CPGMAX];
    __shared__ int re[CPGMAX];
    conv_final_body(a1, a2, w1e, W2, b2, lw, ofs, pairs, out,
                    N, NB, CPG, E, blockIdx.y, blockIdx.x, a1s, acc, rs, re);
}

// ---------------------------------------------------------------------------
// atomic fallback (R3 proven path)
// ---------------------------------------------------------------------------

__global__ __launch_bounds__(256) void node_init_kernel(
    const int* __restrict__ nf, const float* __restrict__ act,
    float* __restrict__ x0, int BN) {
    int tid = blockIdx.x * blockDim.x + threadIdx.x;
    if (tid >= BN) return;
    x0[tid * 3 + 0] = (float)nf[tid * 2 + 0];
    x0[tid * 3 + 1] = (float)nf[tid * 2 + 1];
    x0[tid * 3 + 2] = act[tid];
}

template <int D>
__global__ __launch_bounds__(256) void edge_conv_kernel(
    const float* __restrict__ x, const int* __restrict__ ei,
    const float* __restrict__ ea,
    const float* __restrict__ W1, const float* __restrict__ b1,
    const float* __restrict__ W2, const float* __restrict__ b2,
    unsigned int* __restrict__ agg, int E, int N, int B) {
    int tid = blockIdx.x * blockDim.x + threadIdx.x;
    if (tid >= B * E) return;
    int b = tid / E;
    int e = tid - b * E;
    const int* eb = ei + (size_t)b * 2 * E;
    int s = eb[e];
    int d = eb[E + e];
    const float* xi = x + ((size_t)b * N + d) * D;
    const float* xj = x + ((size_t)b * N + s) * D;
    constexpr int M = 2 * D + 1;
    float m[M];
#pragma unroll
    for (int k = 0; k < D; ++k) { m[k] = xi[k]; m[D + k] = xj[k]; }
    m[2 * D] = ea[(size_t)b * E + e];
    float h1[8];
#pragma unroll
    for (int j = 0; j < 8; ++j) h1[j] = b1[j];
#pragma unroll
    for (int k = 0; k < M; ++k) {
        float mk = m[k];
#pragma unroll
        for (int j = 0; j < 8; ++j) h1[j] = fmaf(mk, W1[k * 8 + j], h1[j]);
    }
#pragma unroll
    for (int j = 0; j < 8; ++j) h1[j] = lrelu(h1[j]);
    float h2[8];
#pragma unroll
    for (int j = 0; j < 8; ++j) h2[j] = b2[j];
#pragma unroll
    for (int k = 0; k < 8; ++k) {
        float hk = h1[k];
#pragma unroll
        for (int j = 0; j < 8; ++j) h2[j] = fmaf(hk, W2[k * 8 + j], h2[j]);
    }
    unsigned int* ag = agg + ((size_t)b * N + d) * 8;
#pragma unroll
    for (int j = 0; j < 8; ++j) atomicMin(&ag[j], fmin_encode(h2[j]));
}

__global__ __launch_bounds__(256) void finalize_kernel(
    unsigned int* __restrict__ agg, int total) {
    int tid = blockIdx.x * blockDim.x + threadIdx.x;
    if (tid >= total) return;
    float v = fmin_decode(agg[tid]);
    unsigned int u = __float_as_uint(v);
    if ((u & 0x7F800000u) == 0x7F800000u) v = 0.f;
    ((float*)agg)[tid] = lrelu(v);
}

__global__ __launch_bounds__(256) void pool_kernel(
    const float* __restrict__ x0, const float* __restrict__ h,
    const float* __restrict__ lw, const float* __restrict__ lb,
    float* __restrict__ out, int N) {
    int b = blockIdx.y;
    int n = blockIdx.x * blockDim.x + threadIdx.x;
    float c = 0.f;
    if (n < N) {
        const float* x = x0 + ((size_t)b * N + n) * 3;
        const float* hh = h + ((size_t)b * N + n) * 8;
        c = x[0] * lw[0] + x[1] * lw[1] + x[2] * lw[2];
#pragma unroll
        for (int k = 0; k < 8; ++k) c = fmaf(hh[k], lw[3 + k], c);
        if (n == 0) c += lb[0];
    }
    block_add(c, &out[b]);
}

// ---------------------------------------------------------------------------

static inline size_t align256(size_t x) { return (x + 255) & ~(size_t)255; }

extern "C" void kernel_launch(void* const* d_in, const int* in_sizes, int n_in,
                              void* d_out, int out_size, void* d_ws, size_t ws_size,
                              hipStream_t stream) {
    const int B = 4;
    const int N = in_sizes[1] / B;            // actions [B,N]
    const int E = in_sizes[2] / (2 * B);      // edge_index [B,2,E]

    const int*   nf  = (const int*)d_in[0];
    const float* act = (const float*)d_in[1];
    const int*   ei  = (const int*)d_in[2];   // int32 (JAX x64 disabled)
    const float* ea  = (const float*)d_in[3];
    const float* c1_W1 = (const float*)d_in[4];
    const float* c1_b1 = (const float*)d_in[5];
    const float* c1_W2 = (const float*)d_in[6];
    const float* c1_b2 = (const float*)d_in[7];
    const float* c2_W1 = (const float*)d_in[8];
    const float* c2_b1 = (const float*)d_in[9];
    const float* c2_W2 = (const float*)d_in[10];
    const float* c2_b2 = (const float*)d_in[11];
    const float* c3_W1 = (const float*)d_in[12];
    const float* c3_b1 = (const float*)d_in[13];
    const float* c3_W2 = (const float*)d_in[14];
    const float* c3_b2 = (const float*)d_in[15];
    const float* lw    = (const float*)d_in[16];
    const float* lb    = (const float*)d_in[17];
    float* out = (float*)d_out;

    const int BN = B * N;
    const int BE = B * E;
    const int NB = (N + BS - 1) / BS;
    const int CPG = (E + PCHUNK - 1) / PCHUNK;
    const int initBlocks = (N + PT - 1) / PT;

    // ---- workspace layout ----
    char* ws = (char*)d_ws;
    size_t off = 0;
    float* a1A = (float*)(ws + off);           off += align256((size_t)BN * 8 * 4);
    float* a1B = (float*)(ws + off);           off += align256((size_t)BN * 8 * 4);
    unsigned short* a2A = (unsigned short*)(ws + off); off += align256((size_t)BN * 8 * 2);
    unsigned short* a2B = (unsigned short*)(ws + off); off += align256((size_t)BN * 8 * 2);
    int* ofs    = (int*)(ws + off);    off += align256((size_t)B * (NB + 1) * CPG * 4);
    int2* pairs = (int2*)(ws + off);   off += align256((size_t)BE * 8);
    float* x0   = (float*)(ws + off);  off += align256((size_t)BN * 3 * 4);
    const bool useFast = (off <= ws_size) && (NB <= MAXNB) && (CPG <= CPGMAX) &&
                         (N <= 32768);

    hipMemsetAsync(out, 0, (size_t)B * sizeof(float), stream);

    if (useFast) {
        const int gx = (CPG + initBlocks > NB) ? (CPG + initBlocks) : NB;

        // co-residency check for cooperative launch (host-side only; capture-safe)
        int dev = 0;
        hipGetDevice(&dev);
        int numCU = 0;
        hipDeviceGetAttribute(&numCU, hipDeviceAttributeMultiprocessorCount, dev);
        int occ = 0;
        hipOccupancyMaxActiveBlocksPerMultiprocessor(&occ, mega_kernel, 512, 0);
        const bool canCoop = (occ > 0) && ((size_t)occ * (size_t)numCU >=
                                           (size_t)gx * (size_t)B);

        if (canCoop) {
            MegaParams P;
            P.ei = ei; P.ea = ea; P.pairs = pairs; P.ofs = ofs;
            P.nf = nf; P.act = act;
            P.W11 = c1_W1; P.b11 = c1_b1; P.W21 = c1_W2; P.b21 = c1_b2;
            P.W12 = c2_W1; P.b12 = c2_b1; P.W22 = c2_W2; P.b22 = c2_b2;
            P.W13 = c3_W1; P.b13 = c3_b1; P.W23 = c3_W2; P.b23 = c3_b2;
            P.lw = lw; P.lb = lb;
            P.a1A = a1A; P.a2A = a2A; P.a1B = a1B; P.a2B = a2B;
            P.out = out;
            P.E = E; P.N = N; P.NB = NB; P.CPG = CPG; P.initBlocks = initBlocks;
            void* args[] = {&P};
            hipLaunchCooperativeKernel((void*)mega_kernel, dim3(gx, B),
                                       dim3(512), args, 0, stream);
        } else {
            dim3 pgrid(CPG + initBlocks, B);
            dim3 cgrid(NB, B);
            part_init_kernel<<<pgrid, PT, 0, stream>>>(
                ei, ea, pairs, ofs, nf, act, c1_W1, c1_b1, lw, lb,
                a1A, a2A, out, E, N, NB, CPG);
            conv_mid_kernel<<<cgrid, CT, 0, stream>>>(
                a1A, a2A, c1_W1 + 6 * 8, c1_W2, c1_b2, c2_W1, c2_b1,
                ofs, pairs, a1B, a2B, N, NB, CPG, E);
            conv_mid_kernel<<<cgrid, CT, 0, stream>>>(
                a1B, a2B, c2_W1 + 16 * 8, c2_W2, c2_b2, c3_W1, c3_b1,
                ofs, pairs, a1A, a2A, N, NB, CPG, E);
            conv_final_kernel<<<cgrid, CT, 0, stream>>>(
                a1A, a2A, c3_W1 + 16 * 8, c3_W2, c3_b2, lw,
                ofs, pairs, out, N, NB, CPG, E);
        }
    } else {
        // ---- atomic fallback ----
        const int egrid = (BE + 255) / 256;
        const int aggTotal = BN * 8;
        const int agrid = (aggTotal + 255) / 256;
        const size_t aggBytes = (size_t)aggTotal * 4;
        unsigned int* uA = (unsigned int*)a1A;
        unsigned int* uB = (unsigned int*)a1B;

        node_init_kernel<<<(BN + 255) / 256, 256, 0, stream>>>(nf, act, x0, BN);

        hipMemsetAsync(uA, 0xFF, aggBytes, stream);
        edge_conv_kernel<3><<<egrid, 256, 0, stream>>>(
            x0, ei, ea, c1_W1, c1_b1, c1_W2, c1_b2, uA, E, N, B);
        finalize_kernel<<<agrid, 256, 0, stream>>>(uA, aggTotal);

        hipMemsetAsync(uB, 0xFF, aggBytes, stream);
        edge_conv_kernel<8><<<egrid, 256, 0, stream>>>(
            (const float*)uA, ei, ea, c2_W1, c2_b1, c2_W2, c2_b2, uB, E, N, B);
        finalize_kernel<<<agrid, 256, 0, stream>>>(uB, aggTotal);

        hipMemsetAsync(uA, 0xFF, aggBytes, stream);
        edge_conv_kernel<8><<<egrid, 256, 0, stream>>>(
            (const float*)uB, ei, ea, c3_W1, c3_b1, c3_W2, c3_b2, uA, E, N, B);
        finalize_kernel<<<agrid, 256, 0, stream>>>(uA, aggTotal);

        dim3 plgrid((N + 255) / 256, B);
        pool_kernel<<<plgrid, 256, 0, stream>>>(x0, (const float*)uA, lw, lb, out, N);
    }
}